// Round 4
// baseline (625.706 us; speedup 1.0000x reference)
//
#include <hip/hip_runtime.h>
#include <math.h>

// ---------------------------------------------------------------------------
// xLSTM decoder block, MI355X gfx950.
// Pipeline (all flat (b*12+ch)*1024+l layout):
//  prep:  weights -> bf16 (Wg/upl/upr/down transposed to [n][k])
//  ln1:   x -> xn (fp32)  [skip]
//  fc:    xn -> xc, x1 (fp32)
//  ln2:   x1 -> xn2 (bf16)
//  gemm0: xn2 @ WgT + bg -> gx (bf16, 6144x4096)
//  rec:   MFMA sLSTM per (head, 16 batches): R^T in VGPR B-fragments
//  gemm0: hn @ WupT -> lr (bf16, 6144x2048)
//  gate:  glr = gelu(l)*r (vectorized, fast gelu)
//  gemm2: glr @ WdT + down_b ; epilogue y = silu(xc)*(acc+b+x1)+xn -> yb bf16
//  tail:  FUSED conv1+gelu+LN(len)+conv2+skip.
//         Round-12: R10/R11 spills explained — __launch_bounds__ 2nd arg
//         observed to act as min BLOCKS/CU: (512,4) -> 32 waves/CU -> VGPR
//         cap 64, while the aligned-pair tail needs ~94 live. Fix: (512,2)
//         -> cap 128. Structure unchanged from R11 (aligned pairs (2t,2t+1),
//         dword LDS granularity, funnel-shift taps, transient neighbor
//         loads, zero sentinels, pk-FMA). Same cap relaxation applied to
//         slstm_rec (1024,4 -> 1024,1; grid is 1 block/CU anyway).
// ---------------------------------------------------------------------------

typedef short short8_t __attribute__((ext_vector_type(8)));
typedef float floatx4 __attribute__((ext_vector_type(4)));
typedef float float2_t __attribute__((ext_vector_type(2)));

typedef unsigned int u32;
typedef const __attribute__((address_space(1))) u32 gu32;
typedef __attribute__((address_space(3))) u32 lu32;

static __device__ __forceinline__ float b2f(unsigned short u) {
    unsigned v = ((unsigned)u) << 16;
    return __builtin_bit_cast(float, v);
}
static __device__ __forceinline__ unsigned short f2b(float f) {
    unsigned u = __builtin_bit_cast(unsigned, f);
    u += 0x7FFFu + ((u >> 16) & 1u);   // RNE
    return (unsigned short)(u >> 16);
}
static __device__ __forceinline__ float2_t make2u(unsigned u) {
    float2_t r;
    r.x = __builtin_bit_cast(float, u << 16);
    r.y = __builtin_bit_cast(float, u & 0xFFFF0000u);
    return r;
}
static __device__ __forceinline__ u32 pack2(float a, float b) {
    return ((u32)f2b(b) << 16) | (u32)f2b(a);
}
// tanh-form gelu in sigmoid shape: x*sigma(2u) == 0.5x(1+tanh(u)).
static __device__ __forceinline__ float gelu_fast(float x) {
    float u = 0.7978845608f * x * (1.f + 0.044715f * x * x);
    u = fminf(fmaxf(u, -9.f), 9.f);
    return x * __builtin_amdgcn_rcpf(1.f + __expf(-2.f * u));
}

// --------------------------- weight prep ----------------------------------

__global__ __launch_bounds__(256) void transpose_bf16_k(
    const float* __restrict__ src, unsigned short* __restrict__ dst, int K, int N)
{   // dst[n*K+k] = bf16(src[k*N+n]); grid (N/32, K/32), block 256
    __shared__ unsigned short tl[32][33];
    const int n0 = blockIdx.x * 32, k0 = blockIdx.y * 32;
    const int tx = threadIdx.x & 31, ty = threadIdx.x >> 5;
#pragma unroll
    for (int r = 0; r < 4; r++) {
        int k = ty + r * 8;
        tl[tx][k] = f2b(src[(size_t)(k0 + k) * N + n0 + tx]);
    }
    __syncthreads();
#pragma unroll
    for (int r = 0; r < 4; r++) {
        int n = ty * 4 + r;
        dst[(size_t)(n0 + n) * K + k0 + tx] = tl[n][tx];
    }
}

// ------------------------------ layernorm ----------------------------------

template <int BF16OUT>
__global__ __launch_bounds__(256) void ln_kernel(
    const float* __restrict__ in, const float* __restrict__ g,
    const float* __restrict__ be, void* __restrict__ outp)
{
    const int row = blockIdx.x;
    const float* xr = in + (size_t)row * 1024;
    const int t = threadIdx.x;
    float v[4];
    float s = 0.f, ss = 0.f;
#pragma unroll
    for (int u = 0; u < 4; u++) {
        float q = xr[t + u * 256];
        v[u] = q; s += q; ss += q * q;
    }
#pragma unroll
    for (int off = 32; off >= 1; off >>= 1) {
        s += __shfl_xor(s, off);
        ss += __shfl_xor(ss, off);
    }
    __shared__ float red[8];
    const int wv = t >> 6, la = t & 63;
    if (la == 0) { red[wv] = s; red[4 + wv] = ss; }
    __syncthreads();
    s = red[0] + red[1] + red[2] + red[3];
    ss = red[4] + red[5] + red[6] + red[7];
    float mu = s * (1.f / 1024.f);
    float var = ss * (1.f / 1024.f) - mu * mu;
    float rs = rsqrtf(var + 1e-5f);
#pragma unroll
    for (int u = 0; u < 4; u++) {
        int i = t + u * 256;
        float yv = (v[u] - mu) * rs * g[i] + be[i];
        if (BF16OUT)
            ((unsigned short*)outp)[(size_t)row * 1024 + i] = f2b(yv);
        else
            ((float*)outp)[(size_t)row * 1024 + i] = yv;
    }
}

// ---------------------- fc1 (conv k3) + fc2 (1x1) --------------------------

__global__ __launch_bounds__(256) void fc_kernel(
    const float* __restrict__ xn,
    const float* __restrict__ w1, const float* __restrict__ b1,
    const float* __restrict__ w2, const float* __restrict__ b2,
    float* __restrict__ xc, float* __restrict__ x1)
{
    const int t = threadIdx.x;
    const int gid = blockIdx.x * 256 + t;
    const int b = gid >> 10, l = gid & 1023;
    const float* xb = xn + (size_t)b * 12288;
    float inm[12], in0[12], inp[12];
#pragma unroll
    for (int ci = 0; ci < 12; ci++) {
        in0[ci] = xb[ci * 1024 + l];
        inm[ci] = (l > 0) ? xb[ci * 1024 + l - 1] : 0.f;
        inp[ci] = (l < 1023) ? xb[ci * 1024 + l + 1] : 0.f;
    }
    float xcv[12];
#pragma unroll
    for (int o = 0; o < 12; o++) {
        float a = b1[o];
#pragma unroll
        for (int ci = 0; ci < 12; ci++) {
            const float* wp = w1 + o * 36 + ci * 3;  // uniform -> s_load
            a += inm[ci] * wp[0] + in0[ci] * wp[1] + inp[ci] * wp[2];
        }
        xcv[o] = a;
        xc[(size_t)b * 12288 + o * 1024 + l] = a;
    }
#pragma unroll
    for (int o = 0; o < 12; o++) {
        float a = b2[o];
#pragma unroll
        for (int ci = 0; ci < 12; ci++) a += xcv[ci] * w2[o * 12 + ci];
        x1[(size_t)b * 12288 + o * 1024 + l] = a;
    }
}

// ------------------------------ bf16 GEMM ----------------------------------
// MODE 0: store bf16.  MODE 2: y = silu(xc)*(acc+bias+x1) + skip, store bf16.

template <int MODE>
__global__ __launch_bounds__(256) void gemm_kernel(
    const unsigned short* __restrict__ A, const unsigned short* __restrict__ BT,
    const float* __restrict__ bias, void* __restrict__ out,
    int M, int N, int K,
    const float* __restrict__ xc, const float* __restrict__ x1,
    const float* __restrict__ skip)
{
    __shared__ __align__(16) unsigned short sA[128 * 32];
    __shared__ __align__(16) unsigned short sB[128 * 32];
    const int t = threadIdx.x;
    const int m0 = blockIdx.y * 128;
    const int n0 = blockIdx.x * 128;
    const int w = t >> 6;
    const int lane = t & 63;
    const int wr = (w >> 1) * 64;
    const int wc = (w & 1) * 64;
    const int lrow = lane & 15;
    const int quad = lane >> 4;
    const int row_l = t >> 2;
    const int cs = (t & 3) * 8;

    const unsigned short* gA0 = A + (size_t)(m0 + row_l) * K + cs;
    const unsigned short* gA1 = A + (size_t)(m0 + row_l + 64) * K + cs;
    const unsigned short* gB0 = BT + (size_t)(n0 + row_l) * K + cs;
    const unsigned short* gB1 = BT + (size_t)(n0 + row_l + 64) * K + cs;
    unsigned short* lA0 = sA + w * 512;
    unsigned short* lA1 = sA + 2048 + w * 512;
    unsigned short* lB0 = sB + w * 512;
    unsigned short* lB1 = sB + 2048 + w * 512;

    floatx4 acc[4][4];
#pragma unroll
    for (int i = 0; i < 4; i++)
#pragma unroll
        for (int j = 0; j < 4; j++) acc[i][j] = (floatx4)0.f;

    for (int k0 = 0; k0 < K; k0 += 32) {
        __syncthreads();
        __builtin_amdgcn_global_load_lds((gu32*)(gA0 + k0), (lu32*)lA0, 16, 0, 0);
        __builtin_amdgcn_global_load_lds((gu32*)(gA1 + k0), (lu32*)lA1, 16, 0, 0);
        __builtin_amdgcn_global_load_lds((gu32*)(gB0 + k0), (lu32*)lB0, 16, 0, 0);
        __builtin_amdgcn_global_load_lds((gu32*)(gB1 + k0), (lu32*)lB1, 16, 0, 0);
        __syncthreads();
        short8_t af[4], bfr[4];
#pragma unroll
        for (int i = 0; i < 4; i++) {
            af[i] = *(const short8_t*)(sA + (wr + i * 16 + lrow) * 32 + quad * 8);
            bfr[i] = *(const short8_t*)(sB + (wc + i * 16 + lrow) * 32 + quad * 8);
        }
#pragma unroll
        for (int i = 0; i < 4; i++)
#pragma unroll
            for (int j = 0; j < 4; j++)
                acc[i][j] = __builtin_amdgcn_mfma_f32_16x16x32_bf16(
                    af[i], bfr[j], acc[i][j], 0, 0, 0);
    }

#pragma unroll
    for (int i = 0; i < 4; i++) {
#pragma unroll
        for (int j = 0; j < 4; j++) {
#pragma unroll
            for (int r = 0; r < 4; r++) {
                const int gm = m0 + wr + i * 16 + quad * 4 + r;
                const int gn = n0 + wc + j * 16 + lrow;
                const size_t idx = (size_t)gm * N + gn;
                float v = acc[i][j][r] + bias[gn];
                if (MODE == 0) {
                    ((unsigned short*)out)[idx] = f2b(v);
                } else {
                    float xcv = xc[idx];
                    float sig = xcv * __builtin_amdgcn_rcpf(1.f + __expf(-xcv));
                    ((unsigned short*)out)[idx] =
                        f2b(sig * (v + x1[idx]) + skip[idx]);
                }
            }
        }
    }
}

// ------------------- sLSTM recurrence + GroupNorm (MFMA) -------------------
// grid (NH=8, B/16=32) = 256 blocks (1/CU), block 1024 (16 waves, 4/SIMD).
// Round-12: launch_bounds 2nd arg relaxed to 1 (grid is 1 block/CU anyway);
// the old (1024,4) capped VGPRs at 64 and likely spilled the ~80-reg live set.

#define RECP 516   // f32 row stride for sRec (2-way bank aliasing only)
#define HBP  136   // bf16 row stride for sHb

__global__ __launch_bounds__(1024, 1) void slstm_rec_kernel(
    const float* __restrict__ Rg,             // [8][512][128] f32
    const unsigned short* __restrict__ gxb,   // [B][12][4096] bf16
    const float* __restrict__ gn_g, const float* __restrict__ gn_b,
    unsigned short* __restrict__ hnb)         // [B][12][1024] bf16
{
    __shared__ __align__(16) float sRec[16 * RECP];
    __shared__ __align__(16) unsigned short sHb[16 * HBP];
    const int head = blockIdx.x;
    const int b0 = blockIdx.y * 16;
    const int t = threadIdx.x;
    const int w = t >> 6;
    const int lane = t & 63;
    const int quad = lane >> 4;
    const int l16 = lane & 15;

    short8_t Bf[2][4];
    {
        const float* Rh = Rg + (size_t)head * 65536;
#pragma unroll
        for (int jt = 0; jt < 2; jt++)
#pragma unroll
            for (int kk = 0; kk < 4; kk++) {
                const float* src =
                    Rh + (size_t)(w * 32 + jt * 16 + l16) * 128 + kk * 32 + quad * 8;
                short8_t v;
#pragma unroll
                for (int j = 0; j < 8; j++) v[j] = (short)f2b(src[j]);
                Bf[jt][kk] = v;
            }
    }

    for (int i = t; i < 16 * HBP; i += 1024) sHb[i] = 0;

    const int la = lane;
    float c0 = 0.f, n0s = 0.f, m0 = 0.f;
    float c1 = 0.f, n1s = 0.f, m1 = 0.f;
    const float gg0 = gn_g[head * 128 + la];
    const float gg1 = gn_g[head * 128 + la + 64];
    const float gb0 = gn_b[head * 128 + la];
    const float gb1 = gn_b[head * 128 + la + 64];

    __syncthreads();

    for (int step = 0; step < 12; step++) {
        const unsigned short* gp =
            gxb + ((size_t)(b0 + w) * 12 + step) * 4096 + head * 512;
        float gz0 = b2f(gp[la]),       gz1 = b2f(gp[64 + la]);
        float gi0 = b2f(gp[128 + la]), gi1 = b2f(gp[192 + la]);
        float gf0 = b2f(gp[256 + la]), gf1 = b2f(gp[320 + la]);
        float go0 = b2f(gp[384 + la]), go1 = b2f(gp[448 + la]);

        short8_t Af[4];
#pragma unroll
        for (int kk = 0; kk < 4; kk++)
            Af[kk] = *(const short8_t*)(sHb + l16 * HBP + kk * 32 + quad * 8);
        floatx4 D0 = (floatx4)0.f, D1 = (floatx4)0.f;
#pragma unroll
        for (int kk = 0; kk < 4; kk++) {
            D0 = __builtin_amdgcn_mfma_f32_16x16x32_bf16(Af[kk], Bf[0][kk], D0, 0, 0, 0);
            D1 = __builtin_amdgcn_mfma_f32_16x16x32_bf16(Af[kk], Bf[1][kk], D1, 0, 0, 0);
        }
#pragma unroll
        for (int r = 0; r < 4; r++) {
            sRec[(quad * 4 + r) * RECP + w * 32 + l16] = D0[r];
            sRec[(quad * 4 + r) * RECP + w * 32 + 16 + l16] = D1[r];
        }
        __syncthreads();

        const float* rr = sRec + w * RECP;
        float zp0 = gz0 + rr[la],       zp1 = gz1 + rr[64 + la];
        float ip0 = gi0 + rr[128 + la], ip1 = gi1 + rr[192 + la];
        float fp0 = gf0 + rr[256 + la], fp1 = gf1 + rr[320 + la];
        float op0 = go0 + rr[384 + la], op1 = go1 + rr[448 + la];

        // tanh via sigmoid form + v_rcp (graceful at +/-inf preacts)
        float e20 = __expf(-2.f * zp0), e21 = __expf(-2.f * zp1);
        float z0 = 2.f * __builtin_amdgcn_rcpf(1.f + e20) - 1.f;
        float z1 = 2.f * __builtin_amdgcn_rcpf(1.f + e21) - 1.f;
        float o0 = __builtin_amdgcn_rcpf(1.f + __expf(-op0));
        float o1 = __builtin_amdgcn_rcpf(1.f + __expf(-op1));
        float mn0 = fmaxf(fp0 + m0, ip0), mn1 = fmaxf(fp1 + m1, ip1);
        float ie0 = __expf(ip0 - mn0), ie1 = __expf(ip1 - mn1);
        float fe0 = __expf(fp0 + m0 - mn0), fe1 = __expf(fp1 + m1 - mn1);
        c0 = fe0 * c0 + ie0 * z0;  c1 = fe1 * c1 + ie1 * z1;
        n0s = fe0 * n0s + ie0;     n1s = fe1 * n1s + ie1;
        m0 = mn0;                  m1 = mn1;
        float h0 = o0 * c0 * __builtin_amdgcn_rcpf(n0s);
        float h1 = o1 * c1 * __builtin_amdgcn_rcpf(n1s);

        float s = h0 + h1, ss = h0 * h0 + h1 * h1;
#pragma unroll
        for (int off = 32; off >= 1; off >>= 1) {
            s += __shfl_xor(s, off);
            ss += __shfl_xor(ss, off);
        }
        float mu = s * (1.f / 128.f);
        float var = ss * (1.f / 128.f) - mu * mu;
        float rs = rsqrtf(var + 1e-5f);
        size_t base = ((size_t)(b0 + w) * 12 + step) * 1024 + head * 128;
        hnb[base + la] = f2b((h0 - mu) * rs * gg0 + gb0);
        hnb[base + la + 64] = f2b((h1 - mu) * rs * gg1 + gb1);

        sHb[w * HBP + la] = f2b(h0);
        sHb[w * HBP + la + 64] = f2b(h1);
        __syncthreads();
    }
}

// ------------------------------ gate kernel --------------------------------
// 2 elements/thread via dword loads; grid 12288 x 256.

__global__ __launch_bounds__(256) void gate_kernel(
    const unsigned short* __restrict__ lr, unsigned short* __restrict__ glr)
{
    u32 pi = blockIdx.x * 256 + threadIdx.x;   // pair index, 6144*512 total
    u32 m = pi >> 9, c = pi & 511;
    const u32* row = (const u32*)(lr + (size_t)m * 2048);
    float2_t lf = make2u(row[c]);
    float2_t rt = make2u(row[512 + c]);
    ((u32*)glr)[pi] = pack2(gelu_fast(lf.x) * rt.x, gelu_fast(lf.y) * rt.y);
}

// ---------------- fused tail: conv1+gelu+LN(len)+conv2+skip ----------------
// Round-12: grid 512 (one block per batch), block 512 (8 waves), thread t
// owns ALIGNED positions (2t, 2t+1) -> packed v_pk_fma_f32 math throughout.
// launch_bounds(512, 2): the 2nd arg behaves as min BLOCKS/CU (observed:
// (512,4) pinned VGPR_Count at 64 and spilled the ~94-reg live set ->
// FETCH/WRITE blowup). (512,2) -> 16 waves/CU -> 128-VGPR cap, no spill;
// grid is 2 blocks/CU regardless. Rows padded to 1026 u16 with ZERO
// SENTINELS; neighbor dwords loaded transiently; own gelu dword kept in
// zq[]; funnel-shift recombination for the k=3 taps.

__global__ __launch_bounds__(512, 2) void tail_fused_kernel(
    const unsigned short* __restrict__ y, const float* __restrict__ skip,
    const float* __restrict__ w1, const float* __restrict__ b1,
    const float* __restrict__ w2, const float* __restrict__ b2,
    const float* __restrict__ lng, const float* __restrict__ lnb,
    float* __restrict__ out)
{
    __shared__ unsigned short sYr[2 + 12 * 1026];   // 24.6 KB
    __shared__ unsigned short sZr[2 + 12 * 1026];   // 24.6 KB
    __shared__ float sMR[12][2];
    const int b = blockIdx.x;
    const int t = threadIdx.x;            // dword column; positions 2t, 2t+1
    const size_t boff = (size_t)b * 12288;

    // zero sentinels (tails are never overwritten: data writes stop at u16 1023)
    if (t < 2) { sYr[t] = 0; sZr[t] = 0; }
    if (t < 12) {
        sYr[2 + t * 1026 + 1024] = 0; sYr[2 + t * 1026 + 1025] = 0;
        sZr[2 + t * 1026 + 1024] = 0; sZr[2 + t * 1026 + 1025] = 0;
    }

    u32 dY[12];                           // own y dword per channel
    {
        const u32* gy = (const u32*)(y + boff);
#pragma unroll
        for (int ci = 0; ci < 12; ci++) {
            u32 v = gy[ci * 512 + t];
            dY[ci] = v;
            ((u32*)(sYr + 2 + ci * 1026))[t] = v;
        }
    }
    const float2_t lgp = *(const float2_t*)(lng + 2 * t);
    const float2_t lbp = *(const float2_t*)(lnb + 2 * t);
    __syncthreads();

    float2_t acc[12];
#pragma unroll
    for (int o = 0; o < 12; o++) { float bv = b2[o]; acc[o] = float2_t{bv, bv}; }

    for (int q = 0; q < 4; q++) {
        // ---- conv1: 12 in -> this quarter's 12 out channels; neighbor
        //      dwords loaded transiently (2 live VGPRs, not 24 hoisted)
        float2_t a1[12];
#pragma unroll
        for (int o = 0; o < 12; o++) {
            float bo = b1[q * 12 + o];
            a1[o] = float2_t{bo, bo};
        }
#pragma unroll
        for (int ci = 0; ci < 12; ci++) {
            const u32* rw = (const u32*)(sYr + 2 + ci * 1026);
            u32 ymw = rw[t - 1];                         // edge -> zero sentinel
            u32 ypw = rw[t + 1];
            u32 pm = (ymw >> 16) | (dY[ci] << 16);       // (p-1, p)
            u32 pp = (dY[ci] >> 16) | (ypw << 16);       // (p+1, p+2)
            float2_t vm = make2u(pm);
            float2_t v0 = make2u(dY[ci]);
            float2_t vp = make2u(pp);
            const float* wp = w1 + ci * 3;               // uniform -> SGPR
#pragma unroll
            for (int o = 0; o < 12; o++) {
                const float* wo = wp + (q * 12 + o) * 36;
                a1[o] += vm * wo[0] + v0 * wo[1] + vp * wo[2];
            }
        }
        u32 zq[12];
#pragma unroll
        for (int o = 0; o < 12; o++) {
            u32 pz = pack2(gelu_fast(a1[o].x), gelu_fast(a1[o].y));
            zq[o] = pz;
            ((u32*)(sZr + 2 + o * 1026))[t] = pz;
        }
        __syncthreads();

        // ---- LN stats: wave wv handles ch wv, and ch 8+wv for wv<4
        {
            const int wv = t >> 6, la = t & 63;
#pragma unroll
            for (int j = 0; j < 2; j++) {
                const int ch = wv + j * 8;
                if (ch < 12) {
                    const u32* zr = (const u32*)(sZr + 2 + ch * 1026);
                    float s = 0.f, ss = 0.f;
#pragma unroll
                    for (int u = 0; u < 8; u++) {
                        float2_t v = make2u(zr[la + u * 64]);
                        s += v.x + v.y;
                        ss += v.x * v.x + v.y * v.y;
                    }
#pragma unroll
                    for (int off = 32; off >= 1; off >>= 1) {
                        s += __shfl_xor(s, off);
                        ss += __shfl_xor(ss, off);
                    }
                    if (la == 0) {
                        float mu = s * (1.f / 1024.f);
                        float var = ss * (1.f / 1024.f) - mu * mu;
                        sMR[ch][0] = mu;
                        sMR[ch][1] = rsqrtf(var + 1e-5f);
                    }
                }
            }
        }
        __syncthreads();

        // ---- normalize own dword of each channel (no LDS reads)
#pragma unroll
        for (int ch = 0; ch < 12; ch++) {
            const float mu = sMR[ch][0], rs = sMR[ch][1];
            float2_t f = make2u(zq[ch]);
            f.x = (f.x - mu) * rs * lgp.x + lbp.x;
            f.y = (f.y - mu) * rs * lgp.y + lbp.y;
            u32 pz = pack2(f.x, f.y);
            zq[ch] = pz;
            ((u32*)(sZr + 2 + ch * 1026))[t] = pz;
        }
        __syncthreads();

        // ---- conv2 partial over this quarter's 12 input channels
#pragma unroll
        for (int ci = 0; ci < 12; ci++) {
            const u32* rw = (const u32*)(sZr + 2 + ci * 1026);
            u32 zmw = rw[t - 1];
            u32 zpw = rw[t + 1];
            u32 pm = (zmw >> 16) | (zq[ci] << 16);
            u32 pp = (zq[ci] >> 16) | (zpw << 16);
            float2_t zm = make2u(pm);
            float2_t z0 = make2u(zq[ci]);
            float2_t zp = make2u(pp);
            const float* wp = w2 + (q * 12 + ci) * 3;    // uniform -> SGPR
#pragma unroll
            for (int o = 0; o < 12; o++)
                acc[o] += zm * wp[o * 144] + z0 * wp[o * 144 + 1]
                        + zp * wp[o * 144 + 2];
        }
        __syncthreads();   // before next quarter overwrites sZ
    }

#pragma unroll
    for (int o = 0; o < 12; o++) {
        size_t i0 = boff + (size_t)o * 1024 + 2 * t;
        float2_t sk = *(const float2_t*)(skip + i0);
        float2_t r = acc[o] + sk;
        *(float2_t*)(out + i0) = r;
    }
}

// ------------------------------ launcher -----------------------------------

extern "C" void kernel_launch(void* const* d_in, const int* in_sizes, int n_in,
                              void* d_out, int out_size, void* d_ws, size_t ws_size,
                              hipStream_t stream)
{
    (void)in_sizes; (void)n_in; (void)out_size; (void)ws_size;
    const float* x      = (const float*)d_in[0];
    const float* ln_g   = (const float*)d_in[1];
    const float* ln_b   = (const float*)d_in[2];
    const float* fc1_w  = (const float*)d_in[3];
    const float* fc1_b  = (const float*)d_in[4];
    const float* fc2_w  = (const float*)d_in[5];
    const float* fc2_b  = (const float*)d_in[6];
    const float* conv1_w= (const float*)d_in[7];
    const float* conv1_b= (const float*)d_in[8];
    const float* conv2_w= (const float*)d_in[9];
    const float* conv2_b= (const float*)d_in[10];
    const float* xl_g   = (const float*)d_in[11];
    const float* xl_b   = (const float*)d_in[12];
    const float* Wg     = (const float*)d_in[13];
    const float* bg     = (const float*)d_in[14];
    const float* Rg     = (const float*)d_in[15];
    const float* gn_g   = (const float*)d_in[16];
    const float* gn_b   = (const float*)d_in[17];
    const float* upl_w  = (const float*)d_in[18];
    const float* upl_b  = (const float*)d_in[19];
    const float* upr_w  = (const float*)d_in[20];
    const float* upr_b  = (const float*)d_in[21];
    const float* down_w = (const float*)d_in[22];
    const float* down_b = (const float*)d_in[23];

    char* ws = (char*)d_ws;
    size_t off = 0;
    auto alloc = [&](size_t bytes) -> char* {
        char* p = ws + off;
        off = (off + bytes + 255) & ~(size_t)255;
        return p;
    };
    float* xn            = (float*)alloc(25165824);          // 6144x1024 f32
    float* xc            = (float*)alloc(25165824);
    float* x1            = (float*)alloc(25165824);
    unsigned short* xn2b = (unsigned short*)alloc(12582912); // 6144x1024 bf16
    unsigned short* gxb  = (unsigned short*)alloc(50331648); // 6144x4096 bf16
    unsigned short* hnb  = (unsigned short*)alloc(12582912);
    unsigned short* lrb  = (unsigned short*)alloc(25165824); // 6144x2048 bf16
    unsigned short* glrb = (unsigned short*)alloc(12582912);
    unsigned short* yb   = (unsigned short*)alloc(12582912); // 6144x1024 bf16
    unsigned short* WgT  = (unsigned short*)alloc(8388608);  // 4096x1024 bf16
    unsigned short* WupT = (unsigned short*)alloc(4194304);  // 2048x1024 bf16
    unsigned short* WdT  = (unsigned short*)alloc(2097152);  // 1024x1024 bf16
    float* bup           = (float*)alloc(8192);              // 2048 f32

    // weight prep
    transpose_bf16_k<<<dim3(128, 32), 256, 0, stream>>>(Wg, WgT, 1024, 4096);
    transpose_bf16_k<<<dim3(32, 32), 256, 0, stream>>>(upl_w, WupT, 1024, 1024);
    transpose_bf16_k<<<dim3(32, 32), 256, 0, stream>>>(upr_w, WupT + 1024 * 1024, 1024, 1024);
    transpose_bf16_k<<<dim3(32, 32), 256, 0, stream>>>(down_w, WdT, 1024, 1024);
    {   // bup = [upl_b | upr_b]
        hipMemcpyAsync(bup, upl_b, 4096, hipMemcpyDeviceToDevice, stream);
        hipMemcpyAsync(bup + 1024, upr_b, 4096, hipMemcpyDeviceToDevice, stream);
    }

    // main pipeline
    ln_kernel<0><<<6144, 256, 0, stream>>>(x, ln_g, ln_b, xn);
    fc_kernel<<<2048, 256, 0, stream>>>(xn, fc1_w, fc1_b, fc2_w, fc2_b, xc, x1);
    ln_kernel<1><<<6144, 256, 0, stream>>>(x1, xl_g, xl_b, xn2b);
    gemm_kernel<0><<<dim3(32, 48), 256, 0, stream>>>(
        xn2b, WgT, bg, gxb, 6144, 4096, 1024, nullptr, nullptr, nullptr);
    slstm_rec_kernel<<<dim3(8, 32), 1024, 0, stream>>>(Rg, gxb, gn_g, gn_b, hnb);
    gemm_kernel<0><<<dim3(16, 48), 256, 0, stream>>>(
        hnb, WupT, bup, lrb, 6144, 2048, 1024, nullptr, nullptr, nullptr);
    gate_kernel<<<12288, 256, 0, stream>>>(lrb, glrb);
    gemm_kernel<2><<<dim3(8, 48), 256, 0, stream>>>(
        glrb, WdT, down_b, yb, 6144, 1024, 1024, xc, x1, xn);
    tail_fused_kernel<<<512, 512, 0, stream>>>(
        yb, xn, conv1_w, conv1_b, conv2_w, conv2_b, ln_g, ln_b, (float*)d_out);
}

// Round 5
// 459.329 us; speedup vs baseline: 1.3622x; 1.3622x over previous
//
#include <hip/hip_runtime.h>
#include <math.h>

// ---------------------------------------------------------------------------
// xLSTM decoder block, MI355X gfx950.
// Pipeline (all flat (b*12+ch)*1024+l layout):
//  prep:  weights -> bf16 (Wg/upl/upr/down transposed to [n][k])
//  ln1:   x -> xn (fp32)  [skip]
//  fc:    xn -> xc, x1 (fp32)
//  ln2:   x1 -> xn2 (bf16)
//  gemm0: xn2 @ WgT + bg -> gx (bf16, 6144x4096)
//  rec:   MFMA sLSTM per (head, 16 batches): R^T in VGPR B-fragments
//  gemm0: hn @ WupT -> lr (bf16, 6144x2048)
//  gate:  glr = gelu(l)*r (vectorized, fast gelu)
//  gemm2: glr @ WdT + down_b ; epilogue y = silu(xc)*(acc+b+x1)+xn -> yb bf16
//  tail:  FUSED conv1+gelu+LN(len)+conv2+skip.
//         Round-13: REVERT to the R8 tail verbatim. Evidence: VALU-busy time
//         R8=66us vs R10/R11/R12=131-133us — the aligned-pair/funnel-shift
//         rewrite doubled the issued VALU stream (lost packed-math codegen)
//         independent of spills; launch-bounds tuning then traded occupancy
//         (42%->24%) without touching the 131us busy floor. R8's strided-pair
//         structure (512 thr, pairs (p,p+512), u16 taps, lb(512,6), VGPR 40)
//         is the only measured-cheap instruction stream: 110us.
//         KEPT from R11/R12 (they improved non-tail time 356->322us):
//         rcp-based gelu/sigmoid everywhere, slstm launch_bounds (1024,1).
// ---------------------------------------------------------------------------

typedef short short8_t __attribute__((ext_vector_type(8)));
typedef float floatx4 __attribute__((ext_vector_type(4)));
typedef float float2_t __attribute__((ext_vector_type(2)));

typedef unsigned int u32;
typedef const __attribute__((address_space(1))) u32 gu32;
typedef __attribute__((address_space(3))) u32 lu32;

static __device__ __forceinline__ float b2f(unsigned short u) {
    unsigned v = ((unsigned)u) << 16;
    return __builtin_bit_cast(float, v);
}
static __device__ __forceinline__ unsigned short f2b(float f) {
    unsigned u = __builtin_bit_cast(unsigned, f);
    u += 0x7FFFu + ((u >> 16) & 1u);   // RNE
    return (unsigned short)(u >> 16);
}
static __device__ __forceinline__ float2_t make2u(unsigned u) {
    float2_t r;
    r.x = __builtin_bit_cast(float, u << 16);
    r.y = __builtin_bit_cast(float, u & 0xFFFF0000u);
    return r;
}
static __device__ __forceinline__ u32 pack2(float a, float b) {
    return ((u32)f2b(b) << 16) | (u32)f2b(a);
}
// tanh-form gelu in sigmoid shape: x*sigma(2u) == 0.5x(1+tanh(u)).
static __device__ __forceinline__ float gelu_fast(float x) {
    float u = 0.7978845608f * x * (1.f + 0.044715f * x * x);
    u = fminf(fmaxf(u, -9.f), 9.f);
    return x * __builtin_amdgcn_rcpf(1.f + __expf(-2.f * u));
}

// --------------------------- weight prep ----------------------------------

__global__ __launch_bounds__(256) void transpose_bf16_k(
    const float* __restrict__ src, unsigned short* __restrict__ dst, int K, int N)
{   // dst[n*K+k] = bf16(src[k*N+n]); grid (N/32, K/32), block 256
    __shared__ unsigned short tl[32][33];
    const int n0 = blockIdx.x * 32, k0 = blockIdx.y * 32;
    const int tx = threadIdx.x & 31, ty = threadIdx.x >> 5;
#pragma unroll
    for (int r = 0; r < 4; r++) {
        int k = ty + r * 8;
        tl[tx][k] = f2b(src[(size_t)(k0 + k) * N + n0 + tx]);
    }
    __syncthreads();
#pragma unroll
    for (int r = 0; r < 4; r++) {
        int n = ty * 4 + r;
        dst[(size_t)(n0 + n) * K + k0 + tx] = tl[n][tx];
    }
}

// ------------------------------ layernorm ----------------------------------

template <int BF16OUT>
__global__ __launch_bounds__(256) void ln_kernel(
    const float* __restrict__ in, const float* __restrict__ g,
    const float* __restrict__ be, void* __restrict__ outp)
{
    const int row = blockIdx.x;
    const float* xr = in + (size_t)row * 1024;
    const int t = threadIdx.x;
    float v[4];
    float s = 0.f, ss = 0.f;
#pragma unroll
    for (int u = 0; u < 4; u++) {
        float q = xr[t + u * 256];
        v[u] = q; s += q; ss += q * q;
    }
#pragma unroll
    for (int off = 32; off >= 1; off >>= 1) {
        s += __shfl_xor(s, off);
        ss += __shfl_xor(ss, off);
    }
    __shared__ float red[8];
    const int wv = t >> 6, la = t & 63;
    if (la == 0) { red[wv] = s; red[4 + wv] = ss; }
    __syncthreads();
    s = red[0] + red[1] + red[2] + red[3];
    ss = red[4] + red[5] + red[6] + red[7];
    float mu = s * (1.f / 1024.f);
    float var = ss * (1.f / 1024.f) - mu * mu;
    float rs = rsqrtf(var + 1e-5f);
#pragma unroll
    for (int u = 0; u < 4; u++) {
        int i = t + u * 256;
        float yv = (v[u] - mu) * rs * g[i] + be[i];
        if (BF16OUT)
            ((unsigned short*)outp)[(size_t)row * 1024 + i] = f2b(yv);
        else
            ((float*)outp)[(size_t)row * 1024 + i] = yv;
    }
}

// ---------------------- fc1 (conv k3) + fc2 (1x1) --------------------------

__global__ __launch_bounds__(256) void fc_kernel(
    const float* __restrict__ xn,
    const float* __restrict__ w1, const float* __restrict__ b1,
    const float* __restrict__ w2, const float* __restrict__ b2,
    float* __restrict__ xc, float* __restrict__ x1)
{
    const int t = threadIdx.x;
    const int gid = blockIdx.x * 256 + t;
    const int b = gid >> 10, l = gid & 1023;
    const float* xb = xn + (size_t)b * 12288;
    float inm[12], in0[12], inp[12];
#pragma unroll
    for (int ci = 0; ci < 12; ci++) {
        in0[ci] = xb[ci * 1024 + l];
        inm[ci] = (l > 0) ? xb[ci * 1024 + l - 1] : 0.f;
        inp[ci] = (l < 1023) ? xb[ci * 1024 + l + 1] : 0.f;
    }
    float xcv[12];
#pragma unroll
    for (int o = 0; o < 12; o++) {
        float a = b1[o];
#pragma unroll
        for (int ci = 0; ci < 12; ci++) {
            const float* wp = w1 + o * 36 + ci * 3;  // uniform -> s_load
            a += inm[ci] * wp[0] + in0[ci] * wp[1] + inp[ci] * wp[2];
        }
        xcv[o] = a;
        xc[(size_t)b * 12288 + o * 1024 + l] = a;
    }
#pragma unroll
    for (int o = 0; o < 12; o++) {
        float a = b2[o];
#pragma unroll
        for (int ci = 0; ci < 12; ci++) a += xcv[ci] * w2[o * 12 + ci];
        x1[(size_t)b * 12288 + o * 1024 + l] = a;
    }
}

// ------------------------------ bf16 GEMM ----------------------------------
// MODE 0: store bf16.  MODE 2: y = silu(xc)*(acc+bias+x1) + skip, store bf16.

template <int MODE>
__global__ __launch_bounds__(256) void gemm_kernel(
    const unsigned short* __restrict__ A, const unsigned short* __restrict__ BT,
    const float* __restrict__ bias, void* __restrict__ out,
    int M, int N, int K,
    const float* __restrict__ xc, const float* __restrict__ x1,
    const float* __restrict__ skip)
{
    __shared__ __align__(16) unsigned short sA[128 * 32];
    __shared__ __align__(16) unsigned short sB[128 * 32];
    const int t = threadIdx.x;
    const int m0 = blockIdx.y * 128;
    const int n0 = blockIdx.x * 128;
    const int w = t >> 6;
    const int lane = t & 63;
    const int wr = (w >> 1) * 64;
    const int wc = (w & 1) * 64;
    const int lrow = lane & 15;
    const int quad = lane >> 4;
    const int row_l = t >> 2;
    const int cs = (t & 3) * 8;

    const unsigned short* gA0 = A + (size_t)(m0 + row_l) * K + cs;
    const unsigned short* gA1 = A + (size_t)(m0 + row_l + 64) * K + cs;
    const unsigned short* gB0 = BT + (size_t)(n0 + row_l) * K + cs;
    const unsigned short* gB1 = BT + (size_t)(n0 + row_l + 64) * K + cs;
    unsigned short* lA0 = sA + w * 512;
    unsigned short* lA1 = sA + 2048 + w * 512;
    unsigned short* lB0 = sB + w * 512;
    unsigned short* lB1 = sB + 2048 + w * 512;

    floatx4 acc[4][4];
#pragma unroll
    for (int i = 0; i < 4; i++)
#pragma unroll
        for (int j = 0; j < 4; j++) acc[i][j] = (floatx4)0.f;

    for (int k0 = 0; k0 < K; k0 += 32) {
        __syncthreads();
        __builtin_amdgcn_global_load_lds((gu32*)(gA0 + k0), (lu32*)lA0, 16, 0, 0);
        __builtin_amdgcn_global_load_lds((gu32*)(gA1 + k0), (lu32*)lA1, 16, 0, 0);
        __builtin_amdgcn_global_load_lds((gu32*)(gB0 + k0), (lu32*)lB0, 16, 0, 0);
        __builtin_amdgcn_global_load_lds((gu32*)(gB1 + k0), (lu32*)lB1, 16, 0, 0);
        __syncthreads();
        short8_t af[4], bfr[4];
#pragma unroll
        for (int i = 0; i < 4; i++) {
            af[i] = *(const short8_t*)(sA + (wr + i * 16 + lrow) * 32 + quad * 8);
            bfr[i] = *(const short8_t*)(sB + (wc + i * 16 + lrow) * 32 + quad * 8);
        }
#pragma unroll
        for (int i = 0; i < 4; i++)
#pragma unroll
            for (int j = 0; j < 4; j++)
                acc[i][j] = __builtin_amdgcn_mfma_f32_16x16x32_bf16(
                    af[i], bfr[j], acc[i][j], 0, 0, 0);
    }

#pragma unroll
    for (int i = 0; i < 4; i++) {
#pragma unroll
        for (int j = 0; j < 4; j++) {
#pragma unroll
            for (int r = 0; r < 4; r++) {
                const int gm = m0 + wr + i * 16 + quad * 4 + r;
                const int gn = n0 + wc + j * 16 + lrow;
                const size_t idx = (size_t)gm * N + gn;
                float v = acc[i][j][r] + bias[gn];
                if (MODE == 0) {
                    ((unsigned short*)out)[idx] = f2b(v);
                } else {
                    float xcv = xc[idx];
                    float sig = xcv * __builtin_amdgcn_rcpf(1.f + __expf(-xcv));
                    ((unsigned short*)out)[idx] =
                        f2b(sig * (v + x1[idx]) + skip[idx]);
                }
            }
        }
    }
}

// ------------------- sLSTM recurrence + GroupNorm (MFMA) -------------------
// grid (NH=8, B/16=32) = 256 blocks (1/CU), block 1024 (16 waves, 4/SIMD).
// launch_bounds (1024,1): grid is 1 block/CU anyway; relaxed VGPR cap
// (R12 measured: non-tail pipeline time 347 -> 322us with this change).

#define RECP 516   // f32 row stride for sRec (2-way bank aliasing only)
#define HBP  136   // bf16 row stride for sHb

__global__ __launch_bounds__(1024, 1) void slstm_rec_kernel(
    const float* __restrict__ Rg,             // [8][512][128] f32
    const unsigned short* __restrict__ gxb,   // [B][12][4096] bf16
    const float* __restrict__ gn_g, const float* __restrict__ gn_b,
    unsigned short* __restrict__ hnb)         // [B][12][1024] bf16
{
    __shared__ __align__(16) float sRec[16 * RECP];
    __shared__ __align__(16) unsigned short sHb[16 * HBP];
    const int head = blockIdx.x;
    const int b0 = blockIdx.y * 16;
    const int t = threadIdx.x;
    const int w = t >> 6;
    const int lane = t & 63;
    const int quad = lane >> 4;
    const int l16 = lane & 15;

    short8_t Bf[2][4];
    {
        const float* Rh = Rg + (size_t)head * 65536;
#pragma unroll
        for (int jt = 0; jt < 2; jt++)
#pragma unroll
            for (int kk = 0; kk < 4; kk++) {
                const float* src =
                    Rh + (size_t)(w * 32 + jt * 16 + l16) * 128 + kk * 32 + quad * 8;
                short8_t v;
#pragma unroll
                for (int j = 0; j < 8; j++) v[j] = (short)f2b(src[j]);
                Bf[jt][kk] = v;
            }
    }

    for (int i = t; i < 16 * HBP; i += 1024) sHb[i] = 0;

    const int la = lane;
    float c0 = 0.f, n0s = 0.f, m0 = 0.f;
    float c1 = 0.f, n1s = 0.f, m1 = 0.f;
    const float gg0 = gn_g[head * 128 + la];
    const float gg1 = gn_g[head * 128 + la + 64];
    const float gb0 = gn_b[head * 128 + la];
    const float gb1 = gn_b[head * 128 + la + 64];

    __syncthreads();

    for (int step = 0; step < 12; step++) {
        const unsigned short* gp =
            gxb + ((size_t)(b0 + w) * 12 + step) * 4096 + head * 512;
        float gz0 = b2f(gp[la]),       gz1 = b2f(gp[64 + la]);
        float gi0 = b2f(gp[128 + la]), gi1 = b2f(gp[192 + la]);
        float gf0 = b2f(gp[256 + la]), gf1 = b2f(gp[320 + la]);
        float go0 = b2f(gp[384 + la]), go1 = b2f(gp[448 + la]);

        short8_t Af[4];
#pragma unroll
        for (int kk = 0; kk < 4; kk++)
            Af[kk] = *(const short8_t*)(sHb + l16 * HBP + kk * 32 + quad * 8);
        floatx4 D0 = (floatx4)0.f, D1 = (floatx4)0.f;
#pragma unroll
        for (int kk = 0; kk < 4; kk++) {
            D0 = __builtin_amdgcn_mfma_f32_16x16x32_bf16(Af[kk], Bf[0][kk], D0, 0, 0, 0);
            D1 = __builtin_amdgcn_mfma_f32_16x16x32_bf16(Af[kk], Bf[1][kk], D1, 0, 0, 0);
        }
#pragma unroll
        for (int r = 0; r < 4; r++) {
            sRec[(quad * 4 + r) * RECP + w * 32 + l16] = D0[r];
            sRec[(quad * 4 + r) * RECP + w * 32 + 16 + l16] = D1[r];
        }
        __syncthreads();

        const float* rr = sRec + w * RECP;
        float zp0 = gz0 + rr[la],       zp1 = gz1 + rr[64 + la];
        float ip0 = gi0 + rr[128 + la], ip1 = gi1 + rr[192 + la];
        float fp0 = gf0 + rr[256 + la], fp1 = gf1 + rr[320 + la];
        float op0 = go0 + rr[384 + la], op1 = go1 + rr[448 + la];

        // tanh via sigmoid form + v_rcp (graceful at +/-inf preacts)
        float e20 = __expf(-2.f * zp0), e21 = __expf(-2.f * zp1);
        float z0 = 2.f * __builtin_amdgcn_rcpf(1.f + e20) - 1.f;
        float z1 = 2.f * __builtin_amdgcn_rcpf(1.f + e21) - 1.f;
        float o0 = __builtin_amdgcn_rcpf(1.f + __expf(-op0));
        float o1 = __builtin_amdgcn_rcpf(1.f + __expf(-op1));
        float mn0 = fmaxf(fp0 + m0, ip0), mn1 = fmaxf(fp1 + m1, ip1);
        float ie0 = __expf(ip0 - mn0), ie1 = __expf(ip1 - mn1);
        float fe0 = __expf(fp0 + m0 - mn0), fe1 = __expf(fp1 + m1 - mn1);
        c0 = fe0 * c0 + ie0 * z0;  c1 = fe1 * c1 + ie1 * z1;
        n0s = fe0 * n0s + ie0;     n1s = fe1 * n1s + ie1;
        m0 = mn0;                  m1 = mn1;
        float h0 = o0 * c0 * __builtin_amdgcn_rcpf(n0s);
        float h1 = o1 * c1 * __builtin_amdgcn_rcpf(n1s);

        float s = h0 + h1, ss = h0 * h0 + h1 * h1;
#pragma unroll
        for (int off = 32; off >= 1; off >>= 1) {
            s += __shfl_xor(s, off);
            ss += __shfl_xor(ss, off);
        }
        float mu = s * (1.f / 128.f);
        float var = ss * (1.f / 128.f) - mu * mu;
        float rs = rsqrtf(var + 1e-5f);
        size_t base = ((size_t)(b0 + w) * 12 + step) * 1024 + head * 128;
        hnb[base + la] = f2b((h0 - mu) * rs * gg0 + gb0);
        hnb[base + la + 64] = f2b((h1 - mu) * rs * gg1 + gb1);

        sHb[w * HBP + la] = f2b(h0);
        sHb[w * HBP + la + 64] = f2b(h1);
        __syncthreads();
    }
}

// ------------------------------ gate kernel --------------------------------
// 2 elements/thread via dword loads; grid 12288 x 256.

__global__ __launch_bounds__(256) void gate_kernel(
    const unsigned short* __restrict__ lr, unsigned short* __restrict__ glr)
{
    u32 pi = blockIdx.x * 256 + threadIdx.x;   // pair index, 6144*512 total
    u32 m = pi >> 9, c = pi & 511;
    const u32* row = (const u32*)(lr + (size_t)m * 2048);
    float2_t lf = make2u(row[c]);
    float2_t rt = make2u(row[512 + c]);
    ((u32*)glr)[pi] = pack2(gelu_fast(lf.x) * rt.x, gelu_fast(lf.y) * rt.y);
}

// ---------------- fused tail: conv1+gelu+LN(len)+conv2+skip ----------------
// R8 structure, restored verbatim (measured 110us, VALU-busy 66us, VGPR 40):
// grid 512 (one block per batch), block 512 (8 waves). Thread owns strided
// positions (p, p+512) for conv; normalize pass uses dword mapping (2
// adjacent positions) for single-b32 LDS ops. 12-channel quarters -> sY+sZ
// 49.3 KB LDS. launch_bounds(512,6). Accumulator arrays <= 12 wide.

__global__ __launch_bounds__(512, 6) void tail_fused_kernel(
    const unsigned short* __restrict__ y, const float* __restrict__ skip,
    const float* __restrict__ w1, const float* __restrict__ b1,
    const float* __restrict__ w2, const float* __restrict__ b2,
    const float* __restrict__ lng, const float* __restrict__ lnb,
    float* __restrict__ out)
{
    __shared__ unsigned short sY[12][1026];   // 24.6 KB
    __shared__ unsigned short sZ[12][1026];   // 24.6 KB
    __shared__ float sMR[12][2];
    const int b = blockIdx.x;
    const int t = threadIdx.x;
    const int p = t;                          // positions p, p+512
    const size_t boff = (size_t)b * 12288;

    {
        const u32* gy = (const u32*)(y + boff);
#pragma unroll
        for (int ci = 0; ci < 12; ci++)
            ((u32*)&sY[ci][0])[t] = gy[ci * 512 + t];
    }
    // LN gains for the dword-mapped normalize pass (positions 2t, 2t+1)
    const float lgA = lng[2 * t], lbA = lnb[2 * t];
    const float lgB = lng[2 * t + 1], lbB = lnb[2 * t + 1];
    __syncthreads();

    float2_t acc[12];
#pragma unroll
    for (int o = 0; o < 12; o++) { float bv = b2[o]; acc[o] = float2_t{bv, bv}; }

    for (int q = 0; q < 4; q++) {
        // ---- conv1: 12 in -> this quarter's 12 out channels, ci-outer
        float2_t a1[12];
#pragma unroll
        for (int o = 0; o < 12; o++) {
            float bo = b1[q * 12 + o];
            a1[o] = float2_t{bo, bo};
        }
        for (int ci = 0; ci < 12; ci++) {
            float2_t v0 = float2_t{b2f(sY[ci][p]), b2f(sY[ci][p + 512])};
            float2_t vm = float2_t{(p > 0) ? b2f(sY[ci][p - 1]) : 0.f,
                                   b2f(sY[ci][p + 511])};
            float2_t vp = float2_t{b2f(sY[ci][p + 1]),
                                   (p < 511) ? b2f(sY[ci][p + 513]) : 0.f};
            const float* wp = w1 + ci * 3;             // uniform -> SGPR
#pragma unroll
            for (int o = 0; o < 12; o++) {
                const float* wo = wp + (q * 12 + o) * 36;
                a1[o] += vm * wo[0] + v0 * wo[1] + vp * wo[2];
            }
        }
#pragma unroll
        for (int o = 0; o < 12; o++) {
            sZ[o][p] = f2b(gelu_fast(a1[o].x));
            sZ[o][p + 512] = f2b(gelu_fast(a1[o].y));
        }
        __syncthreads();

        // ---- LN stats: wave wv handles ch wv, and ch 8+wv for wv<4
        {
            const int wv = t >> 6, la = t & 63;
#pragma unroll
            for (int j = 0; j < 2; j++) {
                const int ch = wv + j * 8;
                if (ch < 12) {
                    float s = 0.f, ss = 0.f;
#pragma unroll
                    for (int u = 0; u < 8; u++) {
                        float2_t v = make2u(((const u32*)&sZ[ch][0])[la + u * 64]);
                        s += v.x + v.y;
                        ss += v.x * v.x + v.y * v.y;
                    }
#pragma unroll
                    for (int off = 32; off >= 1; off >>= 1) {
                        s += __shfl_xor(s, off);
                        ss += __shfl_xor(ss, off);
                    }
                    if (la == 0) {
                        float mu = s * (1.f / 1024.f);
                        float var = ss * (1.f / 1024.f) - mu * mu;
                        sMR[ch][0] = mu;
                        sMR[ch][1] = rsqrtf(var + 1e-5f);
                    }
                }
            }
        }
        __syncthreads();

        // ---- normalize in place (dword mapping: one b32 read+write per ch)
#pragma unroll
        for (int ch = 0; ch < 12; ch++) {
            const float mu = sMR[ch][0], rs = sMR[ch][1];
            float2_t f = make2u(((const u32*)&sZ[ch][0])[t]);
            f.x = (f.x - mu) * rs * lgA + lbA;
            f.y = (f.y - mu) * rs * lgB + lbB;
            ((u32*)&sZ[ch][0])[t] = pack2(f.x, f.y);
        }
        __syncthreads();

        // ---- conv2 partial over this quarter's 12 input channels
        for (int ci = 0; ci < 12; ci++) {
            float2_t z0 = float2_t{b2f(sZ[ci][p]), b2f(sZ[ci][p + 512])};
            float2_t zm = float2_t{(p > 0) ? b2f(sZ[ci][p - 1]) : 0.f,
                                   b2f(sZ[ci][p + 511])};
            float2_t zp = float2_t{b2f(sZ[ci][p + 1]),
                                   (p < 511) ? b2f(sZ[ci][p + 513]) : 0.f};
            const float* wp = w2 + (q * 12 + ci) * 3;  // uniform -> SGPR
#pragma unroll
            for (int o = 0; o < 12; o++)
                acc[o] += zm * wp[o * 144] + z0 * wp[o * 144 + 1]
                        + zp * wp[o * 144 + 2];
        }
        __syncthreads();   // before next quarter overwrites sZ
    }

#pragma unroll
    for (int o = 0; o < 12; o++) {
        size_t i0 = boff + (size_t)o * 1024 + p;
        out[i0] = acc[o].x + skip[i0];
        out[i0 + 512] = acc[o].y + skip[i0 + 512];
    }
}

// ------------------------------ launcher -----------------------------------

extern "C" void kernel_launch(void* const* d_in, const int* in_sizes, int n_in,
                              void* d_out, int out_size, void* d_ws, size_t ws_size,
                              hipStream_t stream)
{
    (void)in_sizes; (void)n_in; (void)out_size; (void)ws_size;
    const float* x      = (const float*)d_in[0];
    const float* ln_g   = (const float*)d_in[1];
    const float* ln_b   = (const float*)d_in[2];
    const float* fc1_w  = (const float*)d_in[3];
    const float* fc1_b  = (const float*)d_in[4];
    const float* fc2_w  = (const float*)d_in[5];
    const float* fc2_b  = (const float*)d_in[6];
    const float* conv1_w= (const float*)d_in[7];
    const float* conv1_b= (const float*)d_in[8];
    const float* conv2_w= (const float*)d_in[9];
    const float* conv2_b= (const float*)d_in[10];
    const float* xl_g   = (const float*)d_in[11];
    const float* xl_b   = (const float*)d_in[12];
    const float* Wg     = (const float*)d_in[13];
    const float* bg     = (const float*)d_in[14];
    const float* Rg     = (const float*)d_in[15];
    const float* gn_g   = (const float*)d_in[16];
    const float* gn_b   = (const float*)d_in[17];
    const float* upl_w  = (const float*)d_in[18];
    const float* upl_b  = (const float*)d_in[19];
    const float* upr_w  = (const float*)d_in[20];
    const float* upr_b  = (const float*)d_in[21];
    const float* down_w = (const float*)d_in[22];
    const float* down_b = (const float*)d_in[23];

    char* ws = (char*)d_ws;
    size_t off = 0;
    auto alloc = [&](size_t bytes) -> char* {
        char* p = ws + off;
        off = (off + bytes + 255) & ~(size_t)255;
        return p;
    };
    float* xn            = (float*)alloc(25165824);          // 6144x1024 f32
    float* xc            = (float*)alloc(25165824);
    float* x1            = (float*)alloc(25165824);
    unsigned short* xn2b = (unsigned short*)alloc(12582912); // 6144x1024 bf16
    unsigned short* gxb  = (unsigned short*)alloc(50331648); // 6144x4096 bf16
    unsigned short* hnb  = (unsigned short*)alloc(12582912);
    unsigned short* lrb  = (unsigned short*)alloc(25165824); // 6144x2048 bf16
    unsigned short* glrb = (unsigned short*)alloc(12582912);
    unsigned short* yb   = (unsigned short*)alloc(12582912); // 6144x1024 bf16
    unsigned short* WgT  = (unsigned short*)alloc(8388608);  // 4096x1024 bf16
    unsigned short* WupT = (unsigned short*)alloc(4194304);  // 2048x1024 bf16
    unsigned short* WdT  = (unsigned short*)alloc(2097152);  // 1024x1024 bf16
    float* bup           = (float*)alloc(8192);              // 2048 f32

    // weight prep
    transpose_bf16_k<<<dim3(128, 32), 256, 0, stream>>>(Wg, WgT, 1024, 4096);
    transpose_bf16_k<<<dim3(32, 32), 256, 0, stream>>>(upl_w, WupT, 1024, 1024);
    transpose_bf16_k<<<dim3(32, 32), 256, 0, stream>>>(upr_w, WupT + 1024 * 1024, 1024, 1024);
    transpose_bf16_k<<<dim3(32, 32), 256, 0, stream>>>(down_w, WdT, 1024, 1024);
    {   // bup = [upl_b | upr_b]
        hipMemcpyAsync(bup, upl_b, 4096, hipMemcpyDeviceToDevice, stream);
        hipMemcpyAsync(bup + 1024, upr_b, 4096, hipMemcpyDeviceToDevice, stream);
    }

    // main pipeline
    ln_kernel<0><<<6144, 256, 0, stream>>>(x, ln_g, ln_b, xn);
    fc_kernel<<<2048, 256, 0, stream>>>(xn, fc1_w, fc1_b, fc2_w, fc2_b, xc, x1);
    ln_kernel<1><<<6144, 256, 0, stream>>>(x1, xl_g, xl_b, xn2b);
    gemm_kernel<0><<<dim3(32, 48), 256, 0, stream>>>(
        xn2b, WgT, bg, gxb, 6144, 4096, 1024, nullptr, nullptr, nullptr);
    slstm_rec_kernel<<<dim3(8, 32), 1024, 0, stream>>>(Rg, gxb, gn_g, gn_b, hnb);
    gemm_kernel<0><<<dim3(16, 48), 256, 0, stream>>>(
        hnb, WupT, bup, lrb, 6144, 2048, 1024, nullptr, nullptr, nullptr);
    gate_kernel<<<12288, 256, 0, stream>>>(lrb, glrb);
    gemm_kernel<2><<<dim3(8, 48), 256, 0, stream>>>(
        glrb, WdT, down_b, yb, 6144, 1024, 1024, xc, x1, xn);
    tail_fused_kernel<<<512, 512, 0, stream>>>(
        yb, xn, conv1_w, conv1_b, conv2_w, conv2_b, ln_g, ln_b, (float*)d_out);
}

// Round 6
// 450.180 us; speedup vs baseline: 1.3899x; 1.0203x over previous
//
#include <hip/hip_runtime.h>
#include <math.h>

// ---------------------------------------------------------------------------
// xLSTM decoder block, MI355X gfx950.
// Pipeline (all flat (b*12+ch)*1024+l layout):
//  prep:   weights -> bf16. WgT/WdT plain [n][k]; WupT INTERLEAVED 16-col
//          groups (row (n>>4)*32+(n&15) = upl col n, +16 = upr col n) so
//          gemm1's epilogue holds l and r of the same logical column in
//          acc[i][2k] / acc[i][2k+1]. bup interleaved to match.
//  ln_fc:  FUSED ln1 + fc1(conv k3) + fc2(1x1): x -> xn (skip, f32), xc, x1.
//          Tail-style: LDS f32 stage, per-channel LN stats by wave, zero
//          sentinels for conv 'same' padding, packed-pair conv math.
//  ln2:    x1 -> xn2 (bf16)
//  gemm0:  xn2 @ WgT + bg -> gx (bf16, 6144x4096)
//  rec:    MFMA sLSTM per (head, 16 batches)
//  gemm3:  hn @ WupT(ilv) -> FUSED gate epilogue: glr = gelu(l)*r (bf16,
//          6144x1024). Kills the separate gate kernel + lrb round trip.
//  gemm2:  glr @ WdT + down_b ; epilogue y = silu(xc)*(acc+b+x1)+xn -> yb
//  tail:   FUSED conv1+gelu+LN(len)+conv2+skip — R8/R13 structure verbatim
//          (measured 102.7us, VGPR 40; do not touch).
// ---------------------------------------------------------------------------

typedef short short8_t __attribute__((ext_vector_type(8)));
typedef float floatx4 __attribute__((ext_vector_type(4)));
typedef float float2_t __attribute__((ext_vector_type(2)));

typedef unsigned int u32;
typedef const __attribute__((address_space(1))) u32 gu32;
typedef __attribute__((address_space(3))) u32 lu32;

static __device__ __forceinline__ float b2f(unsigned short u) {
    unsigned v = ((unsigned)u) << 16;
    return __builtin_bit_cast(float, v);
}
static __device__ __forceinline__ unsigned short f2b(float f) {
    unsigned u = __builtin_bit_cast(unsigned, f);
    u += 0x7FFFu + ((u >> 16) & 1u);   // RNE
    return (unsigned short)(u >> 16);
}
static __device__ __forceinline__ float2_t make2u(unsigned u) {
    float2_t r;
    r.x = __builtin_bit_cast(float, u << 16);
    r.y = __builtin_bit_cast(float, u & 0xFFFF0000u);
    return r;
}
static __device__ __forceinline__ u32 pack2(float a, float b) {
    return ((u32)f2b(b) << 16) | (u32)f2b(a);
}
// tanh-form gelu in sigmoid shape: x*sigma(2u) == 0.5x(1+tanh(u)).
static __device__ __forceinline__ float gelu_fast(float x) {
    float u = 0.7978845608f * x * (1.f + 0.044715f * x * x);
    u = fminf(fmaxf(u, -9.f), 9.f);
    return x * __builtin_amdgcn_rcpf(1.f + __expf(-2.f * u));
}

// --------------------------- weight prep ----------------------------------
// dst row = (n>>4)*GS + GO + (n&15). GS=16,GO=0 -> plain transpose.
// GS=32 with GO=0/16 -> 16-col interleave for the fused-gate gemm.

__global__ __launch_bounds__(256) void transpose_bf16_k(
    const float* __restrict__ src, unsigned short* __restrict__ dst,
    int K, int N, int GS, int GO)
{   // grid (N/32, K/32), block 256
    __shared__ unsigned short tl[32][33];
    const int n0 = blockIdx.x * 32, k0 = blockIdx.y * 32;
    const int tx = threadIdx.x & 31, ty = threadIdx.x >> 5;
#pragma unroll
    for (int r = 0; r < 4; r++) {
        int k = ty + r * 8;
        tl[tx][k] = f2b(src[(size_t)(k0 + k) * N + n0 + tx]);
    }
    __syncthreads();
#pragma unroll
    for (int r = 0; r < 4; r++) {
        int n = n0 + ty * 4 + r;
        size_t row = (size_t)((n >> 4) * GS + GO + (n & 15));
        dst[row * K + k0 + tx] = tl[ty * 4 + r][tx];
    }
}

__global__ __launch_bounds__(256) void bias_ilv_kernel(
    const float* __restrict__ bl, const float* __restrict__ br,
    float* __restrict__ o)
{   // o[2048] interleaved to match WupT rows
    int i = blockIdx.x * 256 + threadIdx.x;
    int grp = i >> 5, w = i & 31;
    o[i] = (w < 16) ? bl[grp * 16 + w] : br[grp * 16 + (w - 16)];
}

// ------------------------------ layernorm ----------------------------------

template <int BF16OUT>
__global__ __launch_bounds__(256) void ln_kernel(
    const float* __restrict__ in, const float* __restrict__ g,
    const float* __restrict__ be, void* __restrict__ outp)
{
    const int row = blockIdx.x;
    const float* xr = in + (size_t)row * 1024;
    const int t = threadIdx.x;
    float v[4];
    float s = 0.f, ss = 0.f;
#pragma unroll
    for (int u = 0; u < 4; u++) {
        float q = xr[t + u * 256];
        v[u] = q; s += q; ss += q * q;
    }
#pragma unroll
    for (int off = 32; off >= 1; off >>= 1) {
        s += __shfl_xor(s, off);
        ss += __shfl_xor(ss, off);
    }
    __shared__ float red[8];
    const int wv = t >> 6, la = t & 63;
    if (la == 0) { red[wv] = s; red[4 + wv] = ss; }
    __syncthreads();
    s = red[0] + red[1] + red[2] + red[3];
    ss = red[4] + red[5] + red[6] + red[7];
    float mu = s * (1.f / 1024.f);
    float var = ss * (1.f / 1024.f) - mu * mu;
    float rs = rsqrtf(var + 1e-5f);
#pragma unroll
    for (int u = 0; u < 4; u++) {
        int i = t + u * 256;
        float yv = (v[u] - mu) * rs * g[i] + be[i];
        if (BF16OUT)
            ((unsigned short*)outp)[(size_t)row * 1024 + i] = f2b(yv);
        else
            ((float*)outp)[(size_t)row * 1024 + i] = yv;
    }
}

// ------------- FUSED ln1 + fc1 (conv k3) + fc2 (1x1) -----------------------
// grid 512 (one block per batch), block 512 (8 waves), thread owns strided
// positions (p, p+512). LDS f32 stage with zero sentinels at [0] and [1025]
// (data at [1..1024]) so conv 'same' zero-padding needs no conditionals.

__global__ __launch_bounds__(512, 3) void ln_fc_kernel(
    const float* __restrict__ x,
    const float* __restrict__ g, const float* __restrict__ be,
    const float* __restrict__ w1, const float* __restrict__ b1,
    const float* __restrict__ w2, const float* __restrict__ b2,
    float* __restrict__ xn, float* __restrict__ xc, float* __restrict__ x1)
{
    __shared__ float sX[12][1028];   // 49.3 KB
    __shared__ float sMR[12][2];
    const int b = blockIdx.x;
    const int t = threadIdx.x;
    const int p = t;                 // positions p, p+512
    const size_t boff = (size_t)b * 12288;

    if (t < 12) { sX[t][0] = 0.f; sX[t][1025] = 0.f; sX[t][1026] = 0.f; sX[t][1027] = 0.f; }
    {
        const float* gx = x + boff;
#pragma unroll
        for (int ci = 0; ci < 12; ci++) {
            sX[ci][1 + p] = gx[ci * 1024 + p];
            sX[ci][1 + p + 512] = gx[ci * 1024 + p + 512];
        }
    }
    __syncthreads();

    // ---- LN stats: wave wv handles ch wv, and ch 8+wv for wv<4
    {
        const int wv = t >> 6, la = t & 63;
#pragma unroll
        for (int j = 0; j < 2; j++) {
            const int ch = wv + j * 8;
            if (ch < 12) {
                float s = 0.f, ss = 0.f;
#pragma unroll
                for (int u = 0; u < 16; u++) {
                    float v = sX[ch][1 + la + u * 64];
                    s += v; ss += v * v;
                }
#pragma unroll
                for (int off = 32; off >= 1; off >>= 1) {
                    s += __shfl_xor(s, off);
                    ss += __shfl_xor(ss, off);
                }
                if (la == 0) {
                    float mu = s * (1.f / 1024.f);
                    float var = ss * (1.f / 1024.f) - mu * mu;
                    sMR[ch][0] = mu;
                    sMR[ch][1] = rsqrtf(var + 1e-5f);
                }
            }
        }
    }
    __syncthreads();

    // ---- normalize in place + write xn (skip)
    const float gA = g[p], bA = be[p];
    const float gB = g[p + 512], bB = be[p + 512];
#pragma unroll
    for (int ch = 0; ch < 12; ch++) {
        const float mu = sMR[ch][0], rs = sMR[ch][1];
        float v0 = (sX[ch][1 + p] - mu) * rs * gA + bA;
        float v1 = (sX[ch][1 + p + 512] - mu) * rs * gB + bB;
        sX[ch][1 + p] = v0;
        sX[ch][1 + p + 512] = v1;
        xn[boff + (size_t)ch * 1024 + p] = v0;
        xn[boff + (size_t)ch * 1024 + p + 512] = v1;
    }
    __syncthreads();

    // ---- conv1 (k=3): ci-outer, packed pairs
    float2_t a1[12];
#pragma unroll
    for (int o = 0; o < 12; o++) { float bv = b1[o]; a1[o] = float2_t{bv, bv}; }
    for (int ci = 0; ci < 12; ci++) {
        float2_t vm = float2_t{sX[ci][p],     sX[ci][p + 512]};
        float2_t v0 = float2_t{sX[ci][p + 1], sX[ci][p + 513]};
        float2_t vp = float2_t{sX[ci][p + 2], sX[ci][p + 514]};
        const float* wp = w1 + ci * 3;               // uniform -> SGPR
#pragma unroll
        for (int o = 0; o < 12; o++) {
            const float* wo = wp + o * 36;
            a1[o] += vm * wo[0] + v0 * wo[1] + vp * wo[2];
        }
    }
#pragma unroll
    for (int o = 0; o < 12; o++) {
        xc[boff + (size_t)o * 1024 + p] = a1[o].x;
        xc[boff + (size_t)o * 1024 + p + 512] = a1[o].y;
    }

    // ---- fc2 (1x1)
    float2_t a2[12];
#pragma unroll
    for (int o = 0; o < 12; o++) { float bv = b2[o]; a2[o] = float2_t{bv, bv}; }
#pragma unroll
    for (int ci = 0; ci < 12; ci++) {
#pragma unroll
        for (int o = 0; o < 12; o++)
            a2[o] += a1[ci] * w2[o * 12 + ci];
    }
#pragma unroll
    for (int o = 0; o < 12; o++) {
        x1[boff + (size_t)o * 1024 + p] = a2[o].x;
        x1[boff + (size_t)o * 1024 + p + 512] = a2[o].y;
    }
}

// ------------------------------ bf16 GEMM ----------------------------------
// MODE 0: store bf16.
// MODE 2: y = silu(xc)*(acc+bias+x1) + skip, store bf16.
// MODE 3: fused up-gate: B is 16-col interleaved [l|r]; out (N/2 cols) =
//         gelu(l + bias_l) * (r + bias_r), store bf16.

template <int MODE>
__global__ __launch_bounds__(256) void gemm_kernel(
    const unsigned short* __restrict__ A, const unsigned short* __restrict__ BT,
    const float* __restrict__ bias, void* __restrict__ out,
    int M, int N, int K,
    const float* __restrict__ xc, const float* __restrict__ x1,
    const float* __restrict__ skip)
{
    __shared__ __align__(16) unsigned short sA[128 * 32];
    __shared__ __align__(16) unsigned short sB[128 * 32];
    const int t = threadIdx.x;
    const int m0 = blockIdx.y * 128;
    const int n0 = blockIdx.x * 128;
    const int w = t >> 6;
    const int lane = t & 63;
    const int wr = (w >> 1) * 64;
    const int wc = (w & 1) * 64;
    const int lrow = lane & 15;
    const int quad = lane >> 4;
    const int row_l = t >> 2;
    const int cs = (t & 3) * 8;

    const unsigned short* gA0 = A + (size_t)(m0 + row_l) * K + cs;
    const unsigned short* gA1 = A + (size_t)(m0 + row_l + 64) * K + cs;
    const unsigned short* gB0 = BT + (size_t)(n0 + row_l) * K + cs;
    const unsigned short* gB1 = BT + (size_t)(n0 + row_l + 64) * K + cs;
    unsigned short* lA0 = sA + w * 512;
    unsigned short* lA1 = sA + 2048 + w * 512;
    unsigned short* lB0 = sB + w * 512;
    unsigned short* lB1 = sB + 2048 + w * 512;

    floatx4 acc[4][4];
#pragma unroll
    for (int i = 0; i < 4; i++)
#pragma unroll
        for (int j = 0; j < 4; j++) acc[i][j] = (floatx4)0.f;

    for (int k0 = 0; k0 < K; k0 += 32) {
        __syncthreads();
        __builtin_amdgcn_global_load_lds((gu32*)(gA0 + k0), (lu32*)lA0, 16, 0, 0);
        __builtin_amdgcn_global_load_lds((gu32*)(gA1 + k0), (lu32*)lA1, 16, 0, 0);
        __builtin_amdgcn_global_load_lds((gu32*)(gB0 + k0), (lu32*)lB0, 16, 0, 0);
        __builtin_amdgcn_global_load_lds((gu32*)(gB1 + k0), (lu32*)lB1, 16, 0, 0);
        __syncthreads();
        short8_t af[4], bfr[4];
#pragma unroll
        for (int i = 0; i < 4; i++) {
            af[i] = *(const short8_t*)(sA + (wr + i * 16 + lrow) * 32 + quad * 8);
            bfr[i] = *(const short8_t*)(sB + (wc + i * 16 + lrow) * 32 + quad * 8);
        }
#pragma unroll
        for (int i = 0; i < 4; i++)
#pragma unroll
            for (int j = 0; j < 4; j++)
                acc[i][j] = __builtin_amdgcn_mfma_f32_16x16x32_bf16(
                    af[i], bfr[j], acc[i][j], 0, 0, 0);
    }

    if (MODE == 3) {
#pragma unroll
        for (int i = 0; i < 4; i++) {
#pragma unroll
            for (int k = 0; k < 2; k++) {
#pragma unroll
                for (int r = 0; r < 4; r++) {
                    const int gm = m0 + wr + i * 16 + quad * 4 + r;
                    const int pl = n0 + wc + k * 32 + lrow;   // physical l col
                    float lv = acc[i][2 * k][r] + bias[pl];
                    float rv = acc[i][2 * k + 1][r] + bias[pl + 16];
                    const int nlog = (pl >> 5) * 16 + lrow;
                    ((unsigned short*)out)[(size_t)gm * (N >> 1) + nlog] =
                        f2b(gelu_fast(lv) * rv);
                }
            }
        }
    } else {
#pragma unroll
        for (int i = 0; i < 4; i++) {
#pragma unroll
            for (int j = 0; j < 4; j++) {
#pragma unroll
                for (int r = 0; r < 4; r++) {
                    const int gm = m0 + wr + i * 16 + quad * 4 + r;
                    const int gn = n0 + wc + j * 16 + lrow;
                    const size_t idx = (size_t)gm * N + gn;
                    float v = acc[i][j][r] + bias[gn];
                    if (MODE == 0) {
                        ((unsigned short*)out)[idx] = f2b(v);
                    } else {
                        float xcv = xc[idx];
                        float sig = xcv * __builtin_amdgcn_rcpf(1.f + __expf(-xcv));
                        ((unsigned short*)out)[idx] =
                            f2b(sig * (v + x1[idx]) + skip[idx]);
                    }
                }
            }
        }
    }
}

// ------------------- sLSTM recurrence + GroupNorm (MFMA) -------------------
// grid (NH=8, B/16=32) = 256 blocks (1/CU), block 1024 (16 waves, 4/SIMD).

#define RECP 516   // f32 row stride for sRec (2-way bank aliasing only)
#define HBP  136   // bf16 row stride for sHb

__global__ __launch_bounds__(1024, 1) void slstm_rec_kernel(
    const float* __restrict__ Rg,             // [8][512][128] f32
    const unsigned short* __restrict__ gxb,   // [B][12][4096] bf16
    const float* __restrict__ gn_g, const float* __restrict__ gn_b,
    unsigned short* __restrict__ hnb)         // [B][12][1024] bf16
{
    __shared__ __align__(16) float sRec[16 * RECP];
    __shared__ __align__(16) unsigned short sHb[16 * HBP];
    const int head = blockIdx.x;
    const int b0 = blockIdx.y * 16;
    const int t = threadIdx.x;
    const int w = t >> 6;
    const int lane = t & 63;
    const int quad = lane >> 4;
    const int l16 = lane & 15;

    short8_t Bf[2][4];
    {
        const float* Rh = Rg + (size_t)head * 65536;
#pragma unroll
        for (int jt = 0; jt < 2; jt++)
#pragma unroll
            for (int kk = 0; kk < 4; kk++) {
                const float* src =
                    Rh + (size_t)(w * 32 + jt * 16 + l16) * 128 + kk * 32 + quad * 8;
                short8_t v;
#pragma unroll
                for (int j = 0; j < 8; j++) v[j] = (short)f2b(src[j]);
                Bf[jt][kk] = v;
            }
    }

    for (int i = t; i < 16 * HBP; i += 1024) sHb[i] = 0;

    const int la = lane;
    float c0 = 0.f, n0s = 0.f, m0 = 0.f;
    float c1 = 0.f, n1s = 0.f, m1 = 0.f;
    const float gg0 = gn_g[head * 128 + la];
    const float gg1 = gn_g[head * 128 + la + 64];
    const float gb0 = gn_b[head * 128 + la];
    const float gb1 = gn_b[head * 128 + la + 64];

    __syncthreads();

    for (int step = 0; step < 12; step++) {
        const unsigned short* gp =
            gxb + ((size_t)(b0 + w) * 12 + step) * 4096 + head * 512;
        float gz0 = b2f(gp[la]),       gz1 = b2f(gp[64 + la]);
        float gi0 = b2f(gp[128 + la]), gi1 = b2f(gp[192 + la]);
        float gf0 = b2f(gp[256 + la]), gf1 = b2f(gp[320 + la]);
        float go0 = b2f(gp[384 + la]), go1 = b2f(gp[448 + la]);

        short8_t Af[4];
#pragma unroll
        for (int kk = 0; kk < 4; kk++)
            Af[kk] = *(const short8_t*)(sHb + l16 * HBP + kk * 32 + quad * 8);
        floatx4 D0 = (floatx4)0.f, D1 = (floatx4)0.f;
#pragma unroll
        for (int kk = 0; kk < 4; kk++) {
            D0 = __builtin_amdgcn_mfma_f32_16x16x32_bf16(Af[kk], Bf[0][kk], D0, 0, 0, 0);
            D1 = __builtin_amdgcn_mfma_f32_16x16x32_bf16(Af[kk], Bf[1][kk], D1, 0, 0, 0);
        }
#pragma unroll
        for (int r = 0; r < 4; r++) {
            sRec[(quad * 4 + r) * RECP + w * 32 + l16] = D0[r];
            sRec[(quad * 4 + r) * RECP + w * 32 + 16 + l16] = D1[r];
        }
        __syncthreads();

        const float* rr = sRec + w * RECP;
        float zp0 = gz0 + rr[la],       zp1 = gz1 + rr[64 + la];
        float ip0 = gi0 + rr[128 + la], ip1 = gi1 + rr[192 + la];
        float fp0 = gf0 + rr[256 + la], fp1 = gf1 + rr[320 + la];
        float op0 = go0 + rr[384 + la], op1 = go1 + rr[448 + la];

        // tanh via sigmoid form + v_rcp (graceful at +/-inf preacts)
        float e20 = __expf(-2.f * zp0), e21 = __expf(-2.f * zp1);
        float z0 = 2.f * __builtin_amdgcn_rcpf(1.f + e20) - 1.f;
        float z1 = 2.f * __builtin_amdgcn_rcpf(1.f + e21) - 1.f;
        float o0 = __builtin_amdgcn_rcpf(1.f + __expf(-op0));
        float o1 = __builtin_amdgcn_rcpf(1.f + __expf(-op1));
        float mn0 = fmaxf(fp0 + m0, ip0), mn1 = fmaxf(fp1 + m1, ip1);
        float ie0 = __expf(ip0 - mn0), ie1 = __expf(ip1 - mn1);
        float fe0 = __expf(fp0 + m0 - mn0), fe1 = __expf(fp1 + m1 - mn1);
        c0 = fe0 * c0 + ie0 * z0;  c1 = fe1 * c1 + ie1 * z1;
        n0s = fe0 * n0s + ie0;     n1s = fe1 * n1s + ie1;
        m0 = mn0;                  m1 = mn1;
        float h0 = o0 * c0 * __builtin_amdgcn_rcpf(n0s);
        float h1 = o1 * c1 * __builtin_amdgcn_rcpf(n1s);

        float s = h0 + h1, ss = h0 * h0 + h1 * h1;
#pragma unroll
        for (int off = 32; off >= 1; off >>= 1) {
            s += __shfl_xor(s, off);
            ss += __shfl_xor(ss, off);
        }
        float mu = s * (1.f / 128.f);
        float var = ss * (1.f / 128.f) - mu * mu;
        float rs = rsqrtf(var + 1e-5f);
        size_t base = ((size_t)(b0 + w) * 12 + step) * 1024 + head * 128;
        hnb[base + la] = f2b((h0 - mu) * rs * gg0 + gb0);
        hnb[base + la + 64] = f2b((h1 - mu) * rs * gg1 + gb1);

        sHb[w * HBP + la] = f2b(h0);
        sHb[w * HBP + la + 64] = f2b(h1);
        __syncthreads();
    }
}

// ---------------- fused tail: conv1+gelu+LN(len)+conv2+skip ----------------
// R8/R13 structure verbatim (measured 102.7us, VALU-busy ~55us, VGPR 40).

__global__ __launch_bounds__(512, 6) void tail_fused_kernel(
    const unsigned short* __restrict__ y, const float* __restrict__ skip,
    const float* __restrict__ w1, const float* __restrict__ b1,
    const float* __restrict__ w2, const float* __restrict__ b2,
    const float* __restrict__ lng, const float* __restrict__ lnb,
    float* __restrict__ out)
{
    __shared__ unsigned short sY[12][1026];   // 24.6 KB
    __shared__ unsigned short sZ[12][1026];   // 24.6 KB
    __shared__ float sMR[12][2];
    const int b = blockIdx.x;
    const int t = threadIdx.x;
    const int p = t;                          // positions p, p+512
    const size_t boff = (size_t)b * 12288;

    {
        const u32* gy = (const u32*)(y + boff);
#pragma unroll
        for (int ci = 0; ci < 12; ci++)
            ((u32*)&sY[ci][0])[t] = gy[ci * 512 + t];
    }
    // LN gains for the dword-mapped normalize pass (positions 2t, 2t+1)
    const float lgA = lng[2 * t], lbA = lnb[2 * t];
    const float lgB = lng[2 * t + 1], lbB = lnb[2 * t + 1];
    __syncthreads();

    float2_t acc[12];
#pragma unroll
    for (int o = 0; o < 12; o++) { float bv = b2[o]; acc[o] = float2_t{bv, bv}; }

    for (int q = 0; q < 4; q++) {
        // ---- conv1: 12 in -> this quarter's 12 out channels, ci-outer
        float2_t a1[12];
#pragma unroll
        for (int o = 0; o < 12; o++) {
            float bo = b1[q * 12 + o];
            a1[o] = float2_t{bo, bo};
        }
        for (int ci = 0; ci < 12; ci++) {
            float2_t v0 = float2_t{b2f(sY[ci][p]), b2f(sY[ci][p + 512])};
            float2_t vm = float2_t{(p > 0) ? b2f(sY[ci][p - 1]) : 0.f,
                                   b2f(sY[ci][p + 511])};
            float2_t vp = float2_t{b2f(sY[ci][p + 1]),
                                   (p < 511) ? b2f(sY[ci][p + 513]) : 0.f};
            const float* wp = w1 + ci * 3;             // uniform -> SGPR
#pragma unroll
            for (int o = 0; o < 12; o++) {
                const float* wo = wp + (q * 12 + o) * 36;
                a1[o] += vm * wo[0] + v0 * wo[1] + vp * wo[2];
            }
        }
#pragma unroll
        for (int o = 0; o < 12; o++) {
            sZ[o][p] = f2b(gelu_fast(a1[o].x));
            sZ[o][p + 512] = f2b(gelu_fast(a1[o].y));
        }
        __syncthreads();

        // ---- LN stats: wave wv handles ch wv, and ch 8+wv for wv<4
        {
            const int wv = t >> 6, la = t & 63;
#pragma unroll
            for (int j = 0; j < 2; j++) {
                const int ch = wv + j * 8;
                if (ch < 12) {
                    float s = 0.f, ss = 0.f;
#pragma unroll
                    for (int u = 0; u < 8; u++) {
                        float2_t v = make2u(((const u32*)&sZ[ch][0])[la + u * 64]);
                        s += v.x + v.y;
                        ss += v.x * v.x + v.y * v.y;
                    }
#pragma unroll
                    for (int off = 32; off >= 1; off >>= 1) {
                        s += __shfl_xor(s, off);
                        ss += __shfl_xor(ss, off);
                    }
                    if (la == 0) {
                        float mu = s * (1.f / 1024.f);
                        float var = ss * (1.f / 1024.f) - mu * mu;
                        sMR[ch][0] = mu;
                        sMR[ch][1] = rsqrtf(var + 1e-5f);
                    }
                }
            }
        }
        __syncthreads();

        // ---- normalize in place (dword mapping: one b32 read+write per ch)
#pragma unroll
        for (int ch = 0; ch < 12; ch++) {
            const float mu = sMR[ch][0], rs = sMR[ch][1];
            float2_t f = make2u(((const u32*)&sZ[ch][0])[t]);
            f.x = (f.x - mu) * rs * lgA + lbA;
            f.y = (f.y - mu) * rs * lgB + lbB;
            ((u32*)&sZ[ch][0])[t] = pack2(f.x, f.y);
        }
        __syncthreads();

        // ---- conv2 partial over this quarter's 12 input channels
        for (int ci = 0; ci < 12; ci++) {
            float2_t z0 = float2_t{b2f(sZ[ci][p]), b2f(sZ[ci][p + 512])};
            float2_t zm = float2_t{(p > 0) ? b2f(sZ[ci][p - 1]) : 0.f,
                                   b2f(sZ[ci][p + 511])};
            float2_t zp = float2_t{b2f(sZ[ci][p + 1]),
                                   (p < 511) ? b2f(sZ[ci][p + 513]) : 0.f};
            const float* wp = w2 + (q * 12 + ci) * 3;  // uniform -> SGPR
#pragma unroll
            for (int o = 0; o < 12; o++)
                acc[o] += zm * wp[o * 144] + z0 * wp[o * 144 + 1]
                        + zp * wp[o * 144 + 2];
        }
        __syncthreads();   // before next quarter overwrites sZ
    }

#pragma unroll
    for (int o = 0; o < 12; o++) {
        size_t i0 = boff + (size_t)o * 1024 + p;
        out[i0] = acc[o].x + skip[i0];
        out[i0 + 512] = acc[o].y + skip[i0 + 512];
    }
}

// ------------------------------ launcher -----------------------------------

extern "C" void kernel_launch(void* const* d_in, const int* in_sizes, int n_in,
                              void* d_out, int out_size, void* d_ws, size_t ws_size,
                              hipStream_t stream)
{
    (void)in_sizes; (void)n_in; (void)out_size; (void)ws_size;
    const float* x      = (const float*)d_in[0];
    const float* ln_g   = (const float*)d_in[1];
    const float* ln_b   = (const float*)d_in[2];
    const float* fc1_w  = (const float*)d_in[3];
    const float* fc1_b  = (const float*)d_in[4];
    const float* fc2_w  = (const float*)d_in[5];
    const float* fc2_b  = (const float*)d_in[6];
    const float* conv1_w= (const float*)d_in[7];
    const float* conv1_b= (const float*)d_in[8];
    const float* conv2_w= (const float*)d_in[9];
    const float* conv2_b= (const float*)d_in[10];
    const float* xl_g   = (const float*)d_in[11];
    const float* xl_b   = (const float*)d_in[12];
    const float* Wg     = (const float*)d_in[13];
    const float* bg     = (const float*)d_in[14];
    const float* Rg     = (const float*)d_in[15];
    const float* gn_g   = (const float*)d_in[16];
    const float* gn_b   = (const float*)d_in[17];
    const float* upl_w  = (const float*)d_in[18];
    const float* upl_b  = (const float*)d_in[19];
    const float* upr_w  = (const float*)d_in[20];
    const float* upr_b  = (const float*)d_in[21];
    const float* down_w = (const float*)d_in[22];
    const float* down_b = (const float*)d_in[23];

    char* ws = (char*)d_ws;
    size_t off = 0;
    auto alloc = [&](size_t bytes) -> char* {
        char* p = ws + off;
        off = (off + bytes + 255) & ~(size_t)255;
        return p;
    };
    float* xn            = (float*)alloc(25165824);          // 6144x1024 f32
    float* xc            = (float*)alloc(25165824);
    float* x1            = (float*)alloc(25165824);
    unsigned short* xn2b = (unsigned short*)alloc(12582912); // 6144x1024 bf16
    unsigned short* gxb  = (unsigned short*)alloc(50331648); // 6144x4096 bf16
    unsigned short* hnb  = (unsigned short*)alloc(12582912);
    unsigned short* glrb = (unsigned short*)alloc(12582912); // 6144x1024 bf16
    unsigned short* yb   = (unsigned short*)alloc(12582912); // 6144x1024 bf16
    unsigned short* WgT  = (unsigned short*)alloc(8388608);  // 4096x1024 bf16
    unsigned short* WupT = (unsigned short*)alloc(4194304);  // 2048x1024 bf16 (interleaved)
    unsigned short* WdT  = (unsigned short*)alloc(2097152);  // 1024x1024 bf16
    float* bup           = (float*)alloc(8192);              // 2048 f32 (interleaved)

    // weight prep
    transpose_bf16_k<<<dim3(128, 32), 256, 0, stream>>>(Wg, WgT, 1024, 4096, 16, 0);
    transpose_bf16_k<<<dim3(32, 32), 256, 0, stream>>>(upl_w, WupT, 1024, 1024, 32, 0);
    transpose_bf16_k<<<dim3(32, 32), 256, 0, stream>>>(upr_w, WupT, 1024, 1024, 32, 16);
    transpose_bf16_k<<<dim3(32, 32), 256, 0, stream>>>(down_w, WdT, 1024, 1024, 16, 0);
    bias_ilv_kernel<<<8, 256, 0, stream>>>(upl_b, upr_b, bup);

    // main pipeline
    ln_fc_kernel<<<512, 512, 0, stream>>>(
        x, ln_g, ln_b, fc1_w, fc1_b, fc2_w, fc2_b, xn, xc, x1);
    ln_kernel<1><<<6144, 256, 0, stream>>>(x1, xl_g, xl_b, xn2b);
    gemm_kernel<0><<<dim3(32, 48), 256, 0, stream>>>(
        xn2b, WgT, bg, gxb, 6144, 4096, 1024, nullptr, nullptr, nullptr);
    slstm_rec_kernel<<<dim3(8, 32), 1024, 0, stream>>>(Rg, gxb, gn_g, gn_b, hnb);
    gemm_kernel<3><<<dim3(16, 48), 256, 0, stream>>>(
        hnb, WupT, bup, glrb, 6144, 2048, 1024, nullptr, nullptr, nullptr);
    gemm_kernel<2><<<dim3(8, 48), 256, 0, stream>>>(
        glrb, WdT, down_b, yb, 6144, 1024, 1024, xc, x1, xn);
    tail_fused_kernel<<<512, 512, 0, stream>>>(
        yb, xn, conv1_w, conv1_b, conv2_w, conv2_b, ln_g, ln_b, (float*)d_out);
}

// Round 7
// 449.337 us; speedup vs baseline: 1.3925x; 1.0019x over previous
//
#include <hip/hip_runtime.h>
#include <math.h>

// ---------------------------------------------------------------------------
// xLSTM decoder block, MI355X gfx950.
// Pipeline (all flat (b*12+ch)*1024+l layout):
//  prep:   weights -> bf16. WgT/WdT plain [n][k]; WupT INTERLEAVED 16-col
//          groups so gemm3's epilogue holds l/r of the same logical column.
//  ln_fc:  FUSED ln1 + fc1(conv k3) + fc2(1x1) + ln2: x -> xn (skip, f32),
//          xc, x1 (f32), xn2b (bf16). R15: ln2 folded in — x1 LN stats via
//          sX reuse after a barrier, normalize from registers.
//  gemm0:  xn2 @ WgT + bg -> gx (bf16, 6144x4096)
//  rec:    MFMA sLSTM per (head, 16 batches)
//  gemm3:  hn @ WupT(ilv) -> fused gate epilogue: glr = gelu(l)*r
//  gemm2:  glr @ WdT + down_b ; epilogue y = silu(xc)*(acc+b+x1)+xn -> yb
//  tail:   FUSED conv1+gelu+LN(len)+conv2+skip — R8/R13 structure verbatim
//          (measured 102.7us, VGPR 40; do not touch).
//  R15 GEMM: 2-phase double-buffered K-loop (T3-minimum): prologue-stage
//  tile 0; per iter {issue next-tile global_load_lds -> compute current ->
//  one barrier}. Old loop was fully serial (2 barriers, no load/compute
//  overlap). LDS 32 KB.
// ---------------------------------------------------------------------------

typedef short short8_t __attribute__((ext_vector_type(8)));
typedef float floatx4 __attribute__((ext_vector_type(4)));
typedef float float2_t __attribute__((ext_vector_type(2)));

typedef unsigned int u32;
typedef const __attribute__((address_space(1))) u32 gu32;
typedef __attribute__((address_space(3))) u32 lu32;

static __device__ __forceinline__ float b2f(unsigned short u) {
    unsigned v = ((unsigned)u) << 16;
    return __builtin_bit_cast(float, v);
}
static __device__ __forceinline__ unsigned short f2b(float f) {
    unsigned u = __builtin_bit_cast(unsigned, f);
    u += 0x7FFFu + ((u >> 16) & 1u);   // RNE
    return (unsigned short)(u >> 16);
}
static __device__ __forceinline__ float2_t make2u(unsigned u) {
    float2_t r;
    r.x = __builtin_bit_cast(float, u << 16);
    r.y = __builtin_bit_cast(float, u & 0xFFFF0000u);
    return r;
}
static __device__ __forceinline__ u32 pack2(float a, float b) {
    return ((u32)f2b(b) << 16) | (u32)f2b(a);
}
// tanh-form gelu in sigmoid shape: x*sigma(2u) == 0.5x(1+tanh(u)).
static __device__ __forceinline__ float gelu_fast(float x) {
    float u = 0.7978845608f * x * (1.f + 0.044715f * x * x);
    u = fminf(fmaxf(u, -9.f), 9.f);
    return x * __builtin_amdgcn_rcpf(1.f + __expf(-2.f * u));
}

// --------------------------- weight prep ----------------------------------
// dst row = (n>>4)*GS + GO + (n&15). GS=16,GO=0 -> plain transpose.
// GS=32 with GO=0/16 -> 16-col interleave for the fused-gate gemm.

__global__ __launch_bounds__(256) void transpose_bf16_k(
    const float* __restrict__ src, unsigned short* __restrict__ dst,
    int K, int N, int GS, int GO)
{   // grid (N/32, K/32), block 256
    __shared__ unsigned short tl[32][33];
    const int n0 = blockIdx.x * 32, k0 = blockIdx.y * 32;
    const int tx = threadIdx.x & 31, ty = threadIdx.x >> 5;
#pragma unroll
    for (int r = 0; r < 4; r++) {
        int k = ty + r * 8;
        tl[tx][k] = f2b(src[(size_t)(k0 + k) * N + n0 + tx]);
    }
    __syncthreads();
#pragma unroll
    for (int r = 0; r < 4; r++) {
        int n = n0 + ty * 4 + r;
        size_t row = (size_t)((n >> 4) * GS + GO + (n & 15));
        dst[row * K + k0 + tx] = tl[ty * 4 + r][tx];
    }
}

__global__ __launch_bounds__(256) void bias_ilv_kernel(
    const float* __restrict__ bl, const float* __restrict__ br,
    float* __restrict__ o)
{   // o[2048] interleaved to match WupT rows
    int i = blockIdx.x * 256 + threadIdx.x;
    int grp = i >> 5, w = i & 31;
    o[i] = (w < 16) ? bl[grp * 16 + w] : br[grp * 16 + (w - 16)];
}

// ---- FUSED ln1 + fc1 (conv k3) + fc2 (1x1) + ln2 --------------------------
// grid 512 (one block per batch), block 512 (8 waves), thread owns strided
// positions (p, p+512). LDS f32 stage with zero sentinels at [0] and [1025]
// (data at [1..1024]) so conv 'same' zero-padding needs no conditionals.
// After the conv, sX is reused (behind a barrier) to hold x1 for LN2 stats;
// the normalize uses the register copy and writes xn2b bf16 directly.

__global__ __launch_bounds__(512, 2) void ln_fc_kernel(
    const float* __restrict__ x,
    const float* __restrict__ g, const float* __restrict__ be,
    const float* __restrict__ xlg, const float* __restrict__ xlb,
    const float* __restrict__ w1, const float* __restrict__ b1,
    const float* __restrict__ w2, const float* __restrict__ b2,
    float* __restrict__ xn, float* __restrict__ xc, float* __restrict__ x1,
    unsigned short* __restrict__ xn2b)
{
    __shared__ float sX[12][1028];   // 49.3 KB
    __shared__ float sMR[12][2];
    const int b = blockIdx.x;
    const int t = threadIdx.x;
    const int p = t;                 // positions p, p+512
    const size_t boff = (size_t)b * 12288;

    if (t < 12) { sX[t][0] = 0.f; sX[t][1025] = 0.f; sX[t][1026] = 0.f; sX[t][1027] = 0.f; }
    {
        const float* gx = x + boff;
#pragma unroll
        for (int ci = 0; ci < 12; ci++) {
            sX[ci][1 + p] = gx[ci * 1024 + p];
            sX[ci][1 + p + 512] = gx[ci * 1024 + p + 512];
        }
    }
    __syncthreads();

    // ---- LN1 stats: wave wv handles ch wv, and ch 8+wv for wv<4
    {
        const int wv = t >> 6, la = t & 63;
#pragma unroll
        for (int j = 0; j < 2; j++) {
            const int ch = wv + j * 8;
            if (ch < 12) {
                float s = 0.f, ss = 0.f;
#pragma unroll
                for (int u = 0; u < 16; u++) {
                    float v = sX[ch][1 + la + u * 64];
                    s += v; ss += v * v;
                }
#pragma unroll
                for (int off = 32; off >= 1; off >>= 1) {
                    s += __shfl_xor(s, off);
                    ss += __shfl_xor(ss, off);
                }
                if (la == 0) {
                    float mu = s * (1.f / 1024.f);
                    float var = ss * (1.f / 1024.f) - mu * mu;
                    sMR[ch][0] = mu;
                    sMR[ch][1] = rsqrtf(var + 1e-5f);
                }
            }
        }
    }
    __syncthreads();

    // ---- normalize in place + write xn (skip)
    const float gA = g[p], bA = be[p];
    const float gB = g[p + 512], bB = be[p + 512];
#pragma unroll
    for (int ch = 0; ch < 12; ch++) {
        const float mu = sMR[ch][0], rs = sMR[ch][1];
        float v0 = (sX[ch][1 + p] - mu) * rs * gA + bA;
        float v1 = (sX[ch][1 + p + 512] - mu) * rs * gB + bB;
        sX[ch][1 + p] = v0;
        sX[ch][1 + p + 512] = v1;
        xn[boff + (size_t)ch * 1024 + p] = v0;
        xn[boff + (size_t)ch * 1024 + p + 512] = v1;
    }
    __syncthreads();

    // ---- conv1 (k=3): ci-outer, packed pairs
    float2_t a1[12];
#pragma unroll
    for (int o = 0; o < 12; o++) { float bv = b1[o]; a1[o] = float2_t{bv, bv}; }
    for (int ci = 0; ci < 12; ci++) {
        float2_t vm = float2_t{sX[ci][p],     sX[ci][p + 512]};
        float2_t v0 = float2_t{sX[ci][p + 1], sX[ci][p + 513]};
        float2_t vp = float2_t{sX[ci][p + 2], sX[ci][p + 514]};
        const float* wp = w1 + ci * 3;               // uniform -> SGPR
#pragma unroll
        for (int o = 0; o < 12; o++) {
            const float* wo = wp + o * 36;
            a1[o] += vm * wo[0] + v0 * wo[1] + vp * wo[2];
        }
    }
    __syncthreads();   // all tap reads of sX complete before reuse

#pragma unroll
    for (int o = 0; o < 12; o++) {
        xc[boff + (size_t)o * 1024 + p] = a1[o].x;
        xc[boff + (size_t)o * 1024 + p + 512] = a1[o].y;
    }

    // ---- fc2 (1x1); stash x1 into sX for LN2 stats
    float2_t a2[12];
#pragma unroll
    for (int o = 0; o < 12; o++) { float bv = b2[o]; a2[o] = float2_t{bv, bv}; }
#pragma unroll
    for (int ci = 0; ci < 12; ci++) {
#pragma unroll
        for (int o = 0; o < 12; o++)
            a2[o] += a1[ci] * w2[o * 12 + ci];
    }
#pragma unroll
    for (int o = 0; o < 12; o++) {
        x1[boff + (size_t)o * 1024 + p] = a2[o].x;
        x1[boff + (size_t)o * 1024 + p + 512] = a2[o].y;
        sX[o][p] = a2[o].x;
        sX[o][p + 512] = a2[o].y;
    }
    __syncthreads();

    // ---- LN2 stats (plain columns 0..1023)
    {
        const int wv = t >> 6, la = t & 63;
#pragma unroll
        for (int j = 0; j < 2; j++) {
            const int ch = wv + j * 8;
            if (ch < 12) {
                float s = 0.f, ss = 0.f;
#pragma unroll
                for (int u = 0; u < 16; u++) {
                    float v = sX[ch][la + u * 64];
                    s += v; ss += v * v;
                }
#pragma unroll
                for (int off = 32; off >= 1; off >>= 1) {
                    s += __shfl_xor(s, off);
                    ss += __shfl_xor(ss, off);
                }
                if (la == 0) {
                    float mu = s * (1.f / 1024.f);
                    float var = ss * (1.f / 1024.f) - mu * mu;
                    sMR[ch][0] = mu;
                    sMR[ch][1] = rsqrtf(var + 1e-5f);
                }
            }
        }
    }
    __syncthreads();

    // ---- LN2 normalize from registers -> xn2b bf16
    const float xgA = xlg[p], xbA = xlb[p];
    const float xgB = xlg[p + 512], xbB = xlb[p + 512];
#pragma unroll
    for (int ch = 0; ch < 12; ch++) {
        const float mu = sMR[ch][0], rs = sMR[ch][1];
        xn2b[boff + (size_t)ch * 1024 + p] =
            f2b((a2[ch].x - mu) * rs * xgA + xbA);
        xn2b[boff + (size_t)ch * 1024 + p + 512] =
            f2b((a2[ch].y - mu) * rs * xgB + xbB);
    }
}

// ------------------------------ bf16 GEMM ----------------------------------
// MODE 0: store bf16.
// MODE 2: y = silu(xc)*(acc+bias+x1) + skip, store bf16.
// MODE 3: fused up-gate: B is 16-col interleaved [l|r]; out (N/2 cols) =
//         gelu(l + bias_l) * (r + bias_r), store bf16.
// R15: 2-phase double-buffered K-loop — stage tile k+1 BEFORE computing
// tile k; single barrier per K-step (drains vmcnt for the staged tile and
// protects buffer reuse).

template <int MODE>
__global__ __launch_bounds__(256) void gemm_kernel(
    const unsigned short* __restrict__ A, const unsigned short* __restrict__ BT,
    const float* __restrict__ bias, void* __restrict__ out,
    int M, int N, int K,
    const float* __restrict__ xc, const float* __restrict__ x1,
    const float* __restrict__ skip)
{
    __shared__ __align__(16) unsigned short sA[2][128 * 32];  // 16 KB x2
    __shared__ __align__(16) unsigned short sB[2][128 * 32];
    const int t = threadIdx.x;
    const int m0 = blockIdx.y * 128;
    const int n0 = blockIdx.x * 128;
    const int w = t >> 6;
    const int lane = t & 63;
    const int wr = (w >> 1) * 64;
    const int wc = (w & 1) * 64;
    const int lrow = lane & 15;
    const int quad = lane >> 4;
    const int row_l = t >> 2;
    const int cs = (t & 3) * 8;

    const unsigned short* gA0 = A + (size_t)(m0 + row_l) * K + cs;
    const unsigned short* gA1 = A + (size_t)(m0 + row_l + 64) * K + cs;
    const unsigned short* gB0 = BT + (size_t)(n0 + row_l) * K + cs;
    const unsigned short* gB1 = BT + (size_t)(n0 + row_l + 64) * K + cs;

    floatx4 acc[4][4];
#pragma unroll
    for (int i = 0; i < 4; i++)
#pragma unroll
        for (int j = 0; j < 4; j++) acc[i][j] = (floatx4)0.f;

#define GEMM_STAGE(buf, k0)                                                        \
    do {                                                                           \
        __builtin_amdgcn_global_load_lds((gu32*)(gA0 + (k0)),                      \
            (lu32*)(&sA[buf][w * 512]), 16, 0, 0);                                 \
        __builtin_amdgcn_global_load_lds((gu32*)(gA1 + (k0)),                      \
            (lu32*)(&sA[buf][2048 + w * 512]), 16, 0, 0);                          \
        __builtin_amdgcn_global_load_lds((gu32*)(gB0 + (k0)),                      \
            (lu32*)(&sB[buf][w * 512]), 16, 0, 0);                                 \
        __builtin_amdgcn_global_load_lds((gu32*)(gB1 + (k0)),                      \
            (lu32*)(&sB[buf][2048 + w * 512]), 16, 0, 0);                          \
    } while (0)

#define GEMM_COMPUTE(buf)                                                          \
    do {                                                                           \
        short8_t af[4], bfr[4];                                                    \
        _Pragma("unroll")                                                          \
        for (int i = 0; i < 4; i++) {                                              \
            af[i] = *(const short8_t*)(&sA[buf][(wr + i * 16 + lrow) * 32 + quad * 8]); \
            bfr[i] = *(const short8_t*)(&sB[buf][(wc + i * 16 + lrow) * 32 + quad * 8]); \
        }                                                                          \
        _Pragma("unroll")                                                          \
        for (int i = 0; i < 4; i++)                                                \
            _Pragma("unroll")                                                      \
            for (int j = 0; j < 4; j++)                                            \
                acc[i][j] = __builtin_amdgcn_mfma_f32_16x16x32_bf16(               \
                    af[i], bfr[j], acc[i][j], 0, 0, 0);                            \
    } while (0)

    GEMM_STAGE(0, 0);
    __syncthreads();
    int cur = 0;
    for (int k0 = 32; k0 < K; k0 += 32) {
        GEMM_STAGE(cur ^ 1, k0);   // issue next tile
        GEMM_COMPUTE(cur);         // compute current
        __syncthreads();           // drains vmcnt; protects buffer reuse
        cur ^= 1;
    }
    GEMM_COMPUTE(cur);             // last tile

#undef GEMM_STAGE
#undef GEMM_COMPUTE

    if (MODE == 3) {
#pragma unroll
        for (int i = 0; i < 4; i++) {
#pragma unroll
            for (int k = 0; k < 2; k++) {
#pragma unroll
                for (int r = 0; r < 4; r++) {
                    const int gm = m0 + wr + i * 16 + quad * 4 + r;
                    const int pl = n0 + wc + k * 32 + lrow;   // physical l col
                    float lv = acc[i][2 * k][r] + bias[pl];
                    float rv = acc[i][2 * k + 1][r] + bias[pl + 16];
                    const int nlog = (pl >> 5) * 16 + lrow;
                    ((unsigned short*)out)[(size_t)gm * (N >> 1) + nlog] =
                        f2b(gelu_fast(lv) * rv);
                }
            }
        }
    } else {
#pragma unroll
        for (int i = 0; i < 4; i++) {
#pragma unroll
            for (int j = 0; j < 4; j++) {
#pragma unroll
                for (int r = 0; r < 4; r++) {
                    const int gm = m0 + wr + i * 16 + quad * 4 + r;
                    const int gn = n0 + wc + j * 16 + lrow;
                    const size_t idx = (size_t)gm * N + gn;
                    float v = acc[i][j][r] + bias[gn];
                    if (MODE == 0) {
                        ((unsigned short*)out)[idx] = f2b(v);
                    } else {
                        float xcv = xc[idx];
                        float sig = xcv * __builtin_amdgcn_rcpf(1.f + __expf(-xcv));
                        ((unsigned short*)out)[idx] =
                            f2b(sig * (v + x1[idx]) + skip[idx]);
                    }
                }
            }
        }
    }
}

// ------------------- sLSTM recurrence + GroupNorm (MFMA) -------------------
// grid (NH=8, B/16=32) = 256 blocks (1/CU), block 1024 (16 waves, 4/SIMD).

#define RECP 516   // f32 row stride for sRec (2-way bank aliasing only)
#define HBP  136   // bf16 row stride for sHb

__global__ __launch_bounds__(1024, 1) void slstm_rec_kernel(
    const float* __restrict__ Rg,             // [8][512][128] f32
    const unsigned short* __restrict__ gxb,   // [B][12][4096] bf16
    const float* __restrict__ gn_g, const float* __restrict__ gn_b,
    unsigned short* __restrict__ hnb)         // [B][12][1024] bf16
{
    __shared__ __align__(16) float sRec[16 * RECP];
    __shared__ __align__(16) unsigned short sHb[16 * HBP];
    const int head = blockIdx.x;
    const int b0 = blockIdx.y * 16;
    const int t = threadIdx.x;
    const int w = t >> 6;
    const int lane = t & 63;
    const int quad = lane >> 4;
    const int l16 = lane & 15;

    short8_t Bf[2][4];
    {
        const float* Rh = Rg + (size_t)head * 65536;
#pragma unroll
        for (int jt = 0; jt < 2; jt++)
#pragma unroll
            for (int kk = 0; kk < 4; kk++) {
                const float* src =
                    Rh + (size_t)(w * 32 + jt * 16 + l16) * 128 + kk * 32 + quad * 8;
                short8_t v;
#pragma unroll
                for (int j = 0; j < 8; j++) v[j] = (short)f2b(src[j]);
                Bf[jt][kk] = v;
            }
    }

    for (int i = t; i < 16 * HBP; i += 1024) sHb[i] = 0;

    const int la = lane;
    float c0 = 0.f, n0s = 0.f, m0 = 0.f;
    float c1 = 0.f, n1s = 0.f, m1 = 0.f;
    const float gg0 = gn_g[head * 128 + la];
    const float gg1 = gn_g[head * 128 + la + 64];
    const float gb0 = gn_b[head * 128 + la];
    const float gb1 = gn_b[head * 128 + la + 64];

    __syncthreads();

    for (int step = 0; step < 12; step++) {
        const unsigned short* gp =
            gxb + ((size_t)(b0 + w) * 12 + step) * 4096 + head * 512;
        float gz0 = b2f(gp[la]),       gz1 = b2f(gp[64 + la]);
        float gi0 = b2f(gp[128 + la]), gi1 = b2f(gp[192 + la]);
        float gf0 = b2f(gp[256 + la]), gf1 = b2f(gp[320 + la]);
        float go0 = b2f(gp[384 + la]), go1 = b2f(gp[448 + la]);

        short8_t Af[4];
#pragma unroll
        for (int kk = 0; kk < 4; kk++)
            Af[kk] = *(const short8_t*)(sHb + l16 * HBP + kk * 32 + quad * 8);
        floatx4 D0 = (floatx4)0.f, D1 = (floatx4)0.f;
#pragma unroll
        for (int kk = 0; kk < 4; kk++) {
            D0 = __builtin_amdgcn_mfma_f32_16x16x32_bf16(Af[kk], Bf[0][kk], D0, 0, 0, 0);
            D1 = __builtin_amdgcn_mfma_f32_16x16x32_bf16(Af[kk], Bf[1][kk], D1, 0, 0, 0);
        }
#pragma unroll
        for (int r = 0; r < 4; r++) {
            sRec[(quad * 4 + r) * RECP + w * 32 + l16] = D0[r];
            sRec[(quad * 4 + r) * RECP + w * 32 + 16 + l16] = D1[r];
        }
        __syncthreads();

        const float* rr = sRec + w * RECP;
        float zp0 = gz0 + rr[la],       zp1 = gz1 + rr[64 + la];
        float ip0 = gi0 + rr[128 + la], ip1 = gi1 + rr[192 + la];
        float fp0 = gf0 + rr[256 + la], fp1 = gf1 + rr[320 + la];
        float op0 = go0 + rr[384 + la], op1 = go1 + rr[448 + la];

        // tanh via sigmoid form + v_rcp (graceful at +/-inf preacts)
        float e20 = __expf(-2.f * zp0), e21 = __expf(-2.f * zp1);
        float z0 = 2.f * __builtin_amdgcn_rcpf(1.f + e20) - 1.f;
        float z1 = 2.f * __builtin_amdgcn_rcpf(1.f + e21) - 1.f;
        float o0 = __builtin_amdgcn_rcpf(1.f + __expf(-op0));
        float o1 = __builtin_amdgcn_rcpf(1.f + __expf(-op1));
        float mn0 = fmaxf(fp0 + m0, ip0), mn1 = fmaxf(fp1 + m1, ip1);
        float ie0 = __expf(ip0 - mn0), ie1 = __expf(ip1 - mn1);
        float fe0 = __expf(fp0 + m0 - mn0), fe1 = __expf(fp1 + m1 - mn1);
        c0 = fe0 * c0 + ie0 * z0;  c1 = fe1 * c1 + ie1 * z1;
        n0s = fe0 * n0s + ie0;     n1s = fe1 * n1s + ie1;
        m0 = mn0;                  m1 = mn1;
        float h0 = o0 * c0 * __builtin_amdgcn_rcpf(n0s);
        float h1 = o1 * c1 * __builtin_amdgcn_rcpf(n1s);

        float s = h0 + h1, ss = h0 * h0 + h1 * h1;
#pragma unroll
        for (int off = 32; off >= 1; off >>= 1) {
            s += __shfl_xor(s, off);
            ss += __shfl_xor(ss, off);
        }
        float mu = s * (1.f / 128.f);
        float var = ss * (1.f / 128.f) - mu * mu;
        float rs = rsqrtf(var + 1e-5f);
        size_t base = ((size_t)(b0 + w) * 12 + step) * 1024 + head * 128;
        hnb[base + la] = f2b((h0 - mu) * rs * gg0 + gb0);
        hnb[base + la + 64] = f2b((h1 - mu) * rs * gg1 + gb1);

        sHb[w * HBP + la] = f2b(h0);
        sHb[w * HBP + la + 64] = f2b(h1);
        __syncthreads();
    }
}

// ---------------- fused tail: conv1+gelu+LN(len)+conv2+skip ----------------
// R8/R13 structure verbatim (measured 102.7us, VALU-busy ~55us, VGPR 40).

__global__ __launch_bounds__(512, 6) void tail_fused_kernel(
    const unsigned short* __restrict__ y, const float* __restrict__ skip,
    const float* __restrict__ w1, const float* __restrict__ b1,
    const float* __restrict__ w2, const float* __restrict__ b2,
    const float* __restrict__ lng, const float* __restrict__ lnb,
    float* __restrict__ out)
{
    __shared__ unsigned short sY[12][1026];   // 24.6 KB
    __shared__ unsigned short sZ[12][1026];   // 24.6 KB
    __shared__ float sMR[12][2];
    const int b = blockIdx.x;
    const int t = threadIdx.x;
    const int p = t;                          // positions p, p+512
    const size_t boff = (size_t)b * 12288;

    {
        const u32* gy = (const u32*)(y + boff);
#pragma unroll
        for (int ci = 0; ci < 12; ci++)
            ((u32*)&sY[ci][0])[t] = gy[ci * 512 + t];
    }
    // LN gains for the dword-mapped normalize pass (positions 2t, 2t+1)
    const float lgA = lng[2 * t], lbA = lnb[2 * t];
    const float lgB = lng[2 * t + 1], lbB = lnb[2 * t + 1];
    __syncthreads();

    float2_t acc[12];
#pragma unroll
    for (int o = 0; o < 12; o++) { float bv = b2[o]; acc[o] = float2_t{bv, bv}; }

    for (int q = 0; q < 4; q++) {
        // ---- conv1: 12 in -> this quarter's 12 out channels, ci-outer
        float2_t a1[12];
#pragma unroll
        for (int o = 0; o < 12; o++) {
            float bo = b1[q * 12 + o];
            a1[o] = float2_t{bo, bo};
        }
        for (int ci = 0; ci < 12; ci++) {
            float2_t v0 = float2_t{b2f(sY[ci][p]), b2f(sY[ci][p + 512])};
            float2_t vm = float2_t{(p > 0) ? b2f(sY[ci][p - 1]) : 0.f,
                                   b2f(sY[ci][p + 511])};
            float2_t vp = float2_t{b2f(sY[ci][p + 1]),
                                   (p < 511) ? b2f(sY[ci][p + 513]) : 0.f};
            const float* wp = w1 + ci * 3;             // uniform -> SGPR
#pragma unroll
            for (int o = 0; o < 12; o++) {
                const float* wo = wp + (q * 12 + o) * 36;
                a1[o] += vm * wo[0] + v0 * wo[1] + vp * wo[2];
            }
        }
#pragma unroll
        for (int o = 0; o < 12; o++) {
            sZ[o][p] = f2b(gelu_fast(a1[o].x));
            sZ[o][p + 512] = f2b(gelu_fast(a1[o].y));
        }
        __syncthreads();

        // ---- LN stats: wave wv handles ch wv, and ch 8+wv for wv<4
        {
            const int wv = t >> 6, la = t & 63;
#pragma unroll
            for (int j = 0; j < 2; j++) {
                const int ch = wv + j * 8;
                if (ch < 12) {
                    float s = 0.f, ss = 0.f;
#pragma unroll
                    for (int u = 0; u < 8; u++) {
                        float2_t v = make2u(((const u32*)&sZ[ch][0])[la + u * 64]);
                        s += v.x + v.y;
                        ss += v.x * v.x + v.y * v.y;
                    }
#pragma unroll
                    for (int off = 32; off >= 1; off >>= 1) {
                        s += __shfl_xor(s, off);
                        ss += __shfl_xor(ss, off);
                    }
                    if (la == 0) {
                        float mu = s * (1.f / 1024.f);
                        float var = ss * (1.f / 1024.f) - mu * mu;
                        sMR[ch][0] = mu;
                        sMR[ch][1] = rsqrtf(var + 1e-5f);
                    }
                }
            }
        }
        __syncthreads();

        // ---- normalize in place (dword mapping: one b32 read+write per ch)
#pragma unroll
        for (int ch = 0; ch < 12; ch++) {
            const float mu = sMR[ch][0], rs = sMR[ch][1];
            float2_t f = make2u(((const u32*)&sZ[ch][0])[t]);
            f.x = (f.x - mu) * rs * lgA + lbA;
            f.y = (f.y - mu) * rs * lgB + lbB;
            ((u32*)&sZ[ch][0])[t] = pack2(f.x, f.y);
        }
        __syncthreads();

        // ---- conv2 partial over this quarter's 12 input channels
        for (int ci = 0; ci < 12; ci++) {
            float2_t z0 = float2_t{b2f(sZ[ci][p]), b2f(sZ[ci][p + 512])};
            float2_t zm = float2_t{(p > 0) ? b2f(sZ[ci][p - 1]) : 0.f,
                                   b2f(sZ[ci][p + 511])};
            float2_t zp = float2_t{b2f(sZ[ci][p + 1]),
                                   (p < 511) ? b2f(sZ[ci][p + 513]) : 0.f};
            const float* wp = w2 + (q * 12 + ci) * 3;  // uniform -> SGPR
#pragma unroll
            for (int o = 0; o < 12; o++)
                acc[o] += zm * wp[o * 144] + z0 * wp[o * 144 + 1]
                        + zp * wp[o * 144 + 2];
        }
        __syncthreads();   // before next quarter overwrites sZ
    }

#pragma unroll
    for (int o = 0; o < 12; o++) {
        size_t i0 = boff + (size_t)o * 1024 + p;
        out[i0] = acc[o].x + skip[i0];
        out[i0 + 512] = acc[o].y + skip[i0 + 512];
    }
}

// ------------------------------ launcher -----------------------------------

extern "C" void kernel_launch(void* const* d_in, const int* in_sizes, int n_in,
                              void* d_out, int out_size, void* d_ws, size_t ws_size,
                              hipStream_t stream)
{
    (void)in_sizes; (void)n_in; (void)out_size; (void)ws_size;
    const float* x      = (const float*)d_in[0];
    const float* ln_g   = (const float*)d_in[1];
    const float* ln_b   = (const float*)d_in[2];
    const float* fc1_w  = (const float*)d_in[3];
    const float* fc1_b  = (const float*)d_in[4];
    const float* fc2_w  = (const float*)d_in[5];
    const float* fc2_b  = (const float*)d_in[6];
    const float* conv1_w= (const float*)d_in[7];
    const float* conv1_b= (const float*)d_in[8];
    const float* conv2_w= (const float*)d_in[9];
    const float* conv2_b= (const float*)d_in[10];
    const float* xl_g   = (const float*)d_in[11];
    const float* xl_b   = (const float*)d_in[12];
    const float* Wg     = (const float*)d_in[13];
    const float* bg     = (const float*)d_in[14];
    const float* Rg     = (const float*)d_in[15];
    const float* gn_g   = (const float*)d_in[16];
    const float* gn_b   = (const float*)d_in[17];
    const float* upl_w  = (const float*)d_in[18];
    const float* upl_b  = (const float*)d_in[19];
    const float* upr_w  = (const float*)d_in[20];
    const float* upr_b  = (const float*)d_in[21];
    const float* down_w = (const float*)d_in[22];
    const float* down_b = (const float*)d_in[23];

    char* ws = (char*)d_ws;
    size_t off = 0;
    auto alloc = [&](size_t bytes) -> char* {
        char* p = ws + off;
        off = (off + bytes + 255) & ~(size_t)255;
        return p;
    };
    float* xn            = (float*)alloc(25165824);          // 6144x1024 f32
    float* xc            = (float*)alloc(25165824);
    float* x1            = (float*)alloc(25165824);
    unsigned short* xn2b = (unsigned short*)alloc(12582912); // 6144x1024 bf16
    unsigned short* gxb  = (unsigned short*)alloc(50331648); // 6144x4096 bf16
    unsigned short* hnb  = (unsigned short*)alloc(12582912);
    unsigned short* glrb = (unsigned short*)alloc(12582912); // 6144x1024 bf16
    unsigned short* yb   = (unsigned short*)alloc(12582912); // 6144x1024 bf16
    unsigned short* WgT  = (unsigned short*)alloc(8388608);  // 4096x1024 bf16
    unsigned short* WupT = (unsigned short*)alloc(4194304);  // 2048x1024 bf16 (interleaved)
    unsigned short* WdT  = (unsigned short*)alloc(2097152);  // 1024x1024 bf16
    float* bup           = (float*)alloc(8192);              // 2048 f32 (interleaved)

    // weight prep
    transpose_bf16_k<<<dim3(128, 32), 256, 0, stream>>>(Wg, WgT, 1024, 4096, 16, 0);
    transpose_bf16_k<<<dim3(32, 32), 256, 0, stream>>>(upl_w, WupT, 1024, 1024, 32, 0);
    transpose_bf16_k<<<dim3(32, 32), 256, 0, stream>>>(upr_w, WupT, 1024, 1024, 32, 16);
    transpose_bf16_k<<<dim3(32, 32), 256, 0, stream>>>(down_w, WdT, 1024, 1024, 16, 0);
    bias_ilv_kernel<<<8, 256, 0, stream>>>(upl_b, upr_b, bup);

    // main pipeline
    ln_fc_kernel<<<512, 512, 0, stream>>>(
        x, ln_g, ln_b, xl_g, xl_b, fc1_w, fc1_b, fc2_w, fc2_b,
        xn, xc, x1, xn2b);
    gemm_kernel<0><<<dim3(32, 48), 256, 0, stream>>>(
        xn2b, WgT, bg, gxb, 6144, 4096, 1024, nullptr, nullptr, nullptr);
    slstm_rec_kernel<<<dim3(8, 32), 1024, 0, stream>>>(Rg, gxb, gn_g, gn_b, hnb);
    gemm_kernel<3><<<dim3(16, 48), 256, 0, stream>>>(
        hnb, WupT, bup, glrb, 6144, 2048, 1024, nullptr, nullptr, nullptr);
    gemm_kernel<2><<<dim3(8, 48), 256, 0, stream>>>(
        glrb, WdT, down_b, yb, 6144, 1024, 1024, xc, x1, xn);
    tail_fused_kernel<<<512, 512, 0, stream>>>(
        yb, xn, conv1_w, conv1_b, conv2_w, conv2_b, ln_g, ln_b, (float*)d_out);
}

// Round 8
// 445.025 us; speedup vs baseline: 1.4060x; 1.0097x over previous
//
#include <hip/hip_runtime.h>
#include <math.h>

// ---------------------------------------------------------------------------
// xLSTM decoder block, MI355X gfx950.
// Pipeline (all flat (b*12+ch)*1024+l layout):
//  prep:   weights -> bf16. WgT/WdT plain [n][k]; WupT INTERLEAVED 16-col
//          groups so gemm3's epilogue holds l/r of the same logical column.
//  ln_fc:  FUSED ln1 + fc1(conv k3) + fc2(1x1) + ln2: x -> xn (skip, f32),
//          xc, x1 (bf16 — only consumer is gemm2's bf16-output epilogue),
//          xn2b (bf16).
//  gemm0:  xn2 @ WgT + bg -> gx (bf16, 6144x4096)
//  rec:    MFMA sLSTM per (head, 16 batches)
//  gemm3:  hn @ WupT(ilv) -> fused gate epilogue: glr = gelu(l)*r
//  gemm2:  glr @ WdT + down_b ; epilogue y = silu(xc)*(acc+b+x1)+xn -> yb
//  tail:   FUSED conv1+gelu+LN(len)+conv2+skip. R16: 2 HALVES of 24 channels
//          (was 4 quarters of 12) -> 9 barriers instead of 17. The old
//          "24-wide regression" (v4/R7) was the 64-VGPR cap of lb(512,6)
//          spilling a1[24]; lb(512,2) raises the cap to 128 (live ~100).
//          LDS 74 KB still fits the grid-limited 2 blocks/CU.
//          R15 GEMM 2-phase double-buffer kept (neutral, not harmful).
// ---------------------------------------------------------------------------

typedef short short8_t __attribute__((ext_vector_type(8)));
typedef float floatx4 __attribute__((ext_vector_type(4)));
typedef float float2_t __attribute__((ext_vector_type(2)));

typedef unsigned int u32;
typedef const __attribute__((address_space(1))) u32 gu32;
typedef __attribute__((address_space(3))) u32 lu32;

static __device__ __forceinline__ float b2f(unsigned short u) {
    unsigned v = ((unsigned)u) << 16;
    return __builtin_bit_cast(float, v);
}
static __device__ __forceinline__ unsigned short f2b(float f) {
    unsigned u = __builtin_bit_cast(unsigned, f);
    u += 0x7FFFu + ((u >> 16) & 1u);   // RNE
    return (unsigned short)(u >> 16);
}
static __device__ __forceinline__ float2_t make2u(unsigned u) {
    float2_t r;
    r.x = __builtin_bit_cast(float, u << 16);
    r.y = __builtin_bit_cast(float, u & 0xFFFF0000u);
    return r;
}
static __device__ __forceinline__ u32 pack2(float a, float b) {
    return ((u32)f2b(b) << 16) | (u32)f2b(a);
}
// tanh-form gelu in sigmoid shape: x*sigma(2u) == 0.5x(1+tanh(u)).
static __device__ __forceinline__ float gelu_fast(float x) {
    float u = 0.7978845608f * x * (1.f + 0.044715f * x * x);
    u = fminf(fmaxf(u, -9.f), 9.f);
    return x * __builtin_amdgcn_rcpf(1.f + __expf(-2.f * u));
}

// --------------------------- weight prep ----------------------------------
// dst row = (n>>4)*GS + GO + (n&15). GS=16,GO=0 -> plain transpose.
// GS=32 with GO=0/16 -> 16-col interleave for the fused-gate gemm.

__global__ __launch_bounds__(256) void transpose_bf16_k(
    const float* __restrict__ src, unsigned short* __restrict__ dst,
    int K, int N, int GS, int GO)
{   // grid (N/32, K/32), block 256
    __shared__ unsigned short tl[32][33];
    const int n0 = blockIdx.x * 32, k0 = blockIdx.y * 32;
    const int tx = threadIdx.x & 31, ty = threadIdx.x >> 5;
#pragma unroll
    for (int r = 0; r < 4; r++) {
        int k = ty + r * 8;
        tl[tx][k] = f2b(src[(size_t)(k0 + k) * N + n0 + tx]);
    }
    __syncthreads();
#pragma unroll
    for (int r = 0; r < 4; r++) {
        int n = n0 + ty * 4 + r;
        size_t row = (size_t)((n >> 4) * GS + GO + (n & 15));
        dst[row * K + k0 + tx] = tl[ty * 4 + r][tx];
    }
}

__global__ __launch_bounds__(256) void bias_ilv_kernel(
    const float* __restrict__ bl, const float* __restrict__ br,
    float* __restrict__ o)
{   // o[2048] interleaved to match WupT rows
    int i = blockIdx.x * 256 + threadIdx.x;
    int grp = i >> 5, w = i & 31;
    o[i] = (w < 16) ? bl[grp * 16 + w] : br[grp * 16 + (w - 16)];
}

// ---- FUSED ln1 + fc1 (conv k3) + fc2 (1x1) + ln2 --------------------------
// grid 512 (one block per batch), block 512 (8 waves), thread owns strided
// positions (p, p+512). LDS f32 stage with zero sentinels at [0] and [1025]
// (data at [1..1024]) so conv 'same' zero-padding needs no conditionals.
// After the conv, sX is reused (behind a barrier) to hold x1 for LN2 stats;
// the normalize uses the register copy and writes xn2b bf16 directly.
// R16: xc/x1 stored as bf16.

__global__ __launch_bounds__(512, 2) void ln_fc_kernel(
    const float* __restrict__ x,
    const float* __restrict__ g, const float* __restrict__ be,
    const float* __restrict__ xlg, const float* __restrict__ xlb,
    const float* __restrict__ w1, const float* __restrict__ b1,
    const float* __restrict__ w2, const float* __restrict__ b2,
    float* __restrict__ xn, unsigned short* __restrict__ xcb,
    unsigned short* __restrict__ x1b, unsigned short* __restrict__ xn2b)
{
    __shared__ float sX[12][1028];   // 49.3 KB
    __shared__ float sMR[12][2];
    const int b = blockIdx.x;
    const int t = threadIdx.x;
    const int p = t;                 // positions p, p+512
    const size_t boff = (size_t)b * 12288;

    if (t < 12) { sX[t][0] = 0.f; sX[t][1025] = 0.f; sX[t][1026] = 0.f; sX[t][1027] = 0.f; }
    {
        const float* gx = x + boff;
#pragma unroll
        for (int ci = 0; ci < 12; ci++) {
            sX[ci][1 + p] = gx[ci * 1024 + p];
            sX[ci][1 + p + 512] = gx[ci * 1024 + p + 512];
        }
    }
    __syncthreads();

    // ---- LN1 stats: wave wv handles ch wv, and ch 8+wv for wv<4
    {
        const int wv = t >> 6, la = t & 63;
#pragma unroll
        for (int j = 0; j < 2; j++) {
            const int ch = wv + j * 8;
            if (ch < 12) {
                float s = 0.f, ss = 0.f;
#pragma unroll
                for (int u = 0; u < 16; u++) {
                    float v = sX[ch][1 + la + u * 64];
                    s += v; ss += v * v;
                }
#pragma unroll
                for (int off = 32; off >= 1; off >>= 1) {
                    s += __shfl_xor(s, off);
                    ss += __shfl_xor(ss, off);
                }
                if (la == 0) {
                    float mu = s * (1.f / 1024.f);
                    float var = ss * (1.f / 1024.f) - mu * mu;
                    sMR[ch][0] = mu;
                    sMR[ch][1] = rsqrtf(var + 1e-5f);
                }
            }
        }
    }
    __syncthreads();

    // ---- normalize in place + write xn (skip)
    const float gA = g[p], bA = be[p];
    const float gB = g[p + 512], bB = be[p + 512];
#pragma unroll
    for (int ch = 0; ch < 12; ch++) {
        const float mu = sMR[ch][0], rs = sMR[ch][1];
        float v0 = (sX[ch][1 + p] - mu) * rs * gA + bA;
        float v1 = (sX[ch][1 + p + 512] - mu) * rs * gB + bB;
        sX[ch][1 + p] = v0;
        sX[ch][1 + p + 512] = v1;
        xn[boff + (size_t)ch * 1024 + p] = v0;
        xn[boff + (size_t)ch * 1024 + p + 512] = v1;
    }
    __syncthreads();

    // ---- conv1 (k=3): ci-outer, packed pairs
    float2_t a1[12];
#pragma unroll
    for (int o = 0; o < 12; o++) { float bv = b1[o]; a1[o] = float2_t{bv, bv}; }
    for (int ci = 0; ci < 12; ci++) {
        float2_t vm = float2_t{sX[ci][p],     sX[ci][p + 512]};
        float2_t v0 = float2_t{sX[ci][p + 1], sX[ci][p + 513]};
        float2_t vp = float2_t{sX[ci][p + 2], sX[ci][p + 514]};
        const float* wp = w1 + ci * 3;               // uniform -> SGPR
#pragma unroll
        for (int o = 0; o < 12; o++) {
            const float* wo = wp + o * 36;
            a1[o] += vm * wo[0] + v0 * wo[1] + vp * wo[2];
        }
    }
    __syncthreads();   // all tap reads of sX complete before reuse

#pragma unroll
    for (int o = 0; o < 12; o++) {
        xcb[boff + (size_t)o * 1024 + p] = f2b(a1[o].x);
        xcb[boff + (size_t)o * 1024 + p + 512] = f2b(a1[o].y);
    }

    // ---- fc2 (1x1); stash x1 into sX for LN2 stats
    float2_t a2[12];
#pragma unroll
    for (int o = 0; o < 12; o++) { float bv = b2[o]; a2[o] = float2_t{bv, bv}; }
#pragma unroll
    for (int ci = 0; ci < 12; ci++) {
#pragma unroll
        for (int o = 0; o < 12; o++)
            a2[o] += a1[ci] * w2[o * 12 + ci];
    }
#pragma unroll
    for (int o = 0; o < 12; o++) {
        x1b[boff + (size_t)o * 1024 + p] = f2b(a2[o].x);
        x1b[boff + (size_t)o * 1024 + p + 512] = f2b(a2[o].y);
        sX[o][p] = a2[o].x;
        sX[o][p + 512] = a2[o].y;
    }
    __syncthreads();

    // ---- LN2 stats (plain columns 0..1023)
    {
        const int wv = t >> 6, la = t & 63;
#pragma unroll
        for (int j = 0; j < 2; j++) {
            const int ch = wv + j * 8;
            if (ch < 12) {
                float s = 0.f, ss = 0.f;
#pragma unroll
                for (int u = 0; u < 16; u++) {
                    float v = sX[ch][la + u * 64];
                    s += v; ss += v * v;
                }
#pragma unroll
                for (int off = 32; off >= 1; off >>= 1) {
                    s += __shfl_xor(s, off);
                    ss += __shfl_xor(ss, off);
                }
                if (la == 0) {
                    float mu = s * (1.f / 1024.f);
                    float var = ss * (1.f / 1024.f) - mu * mu;
                    sMR[ch][0] = mu;
                    sMR[ch][1] = rsqrtf(var + 1e-5f);
                }
            }
        }
    }
    __syncthreads();

    // ---- LN2 normalize from registers -> xn2b bf16
    const float xgA = xlg[p], xbA = xlb[p];
    const float xgB = xlg[p + 512], xbB = xlb[p + 512];
#pragma unroll
    for (int ch = 0; ch < 12; ch++) {
        const float mu = sMR[ch][0], rs = sMR[ch][1];
        xn2b[boff + (size_t)ch * 1024 + p] =
            f2b((a2[ch].x - mu) * rs * xgA + xbA);
        xn2b[boff + (size_t)ch * 1024 + p + 512] =
            f2b((a2[ch].y - mu) * rs * xgB + xbB);
    }
}

// ------------------------------ bf16 GEMM ----------------------------------
// MODE 0: store bf16.
// MODE 2: y = silu(xc)*(acc+bias+x1) + skip, store bf16 (xc/x1 bf16).
// MODE 3: fused up-gate: B is 16-col interleaved [l|r]; out (N/2 cols) =
//         gelu(l + bias_l) * (r + bias_r), store bf16.
// 2-phase double-buffered K-loop.

template <int MODE>
__global__ __launch_bounds__(256) void gemm_kernel(
    const unsigned short* __restrict__ A, const unsigned short* __restrict__ BT,
    const float* __restrict__ bias, void* __restrict__ out,
    int M, int N, int K,
    const unsigned short* __restrict__ xcb, const unsigned short* __restrict__ x1b,
    const float* __restrict__ skip)
{
    __shared__ __align__(16) unsigned short sA[2][128 * 32];  // 8 KB x2
    __shared__ __align__(16) unsigned short sB[2][128 * 32];
    const int t = threadIdx.x;
    const int m0 = blockIdx.y * 128;
    const int n0 = blockIdx.x * 128;
    const int w = t >> 6;
    const int lane = t & 63;
    const int wr = (w >> 1) * 64;
    const int wc = (w & 1) * 64;
    const int lrow = lane & 15;
    const int quad = lane >> 4;
    const int row_l = t >> 2;
    const int cs = (t & 3) * 8;

    const unsigned short* gA0 = A + (size_t)(m0 + row_l) * K + cs;
    const unsigned short* gA1 = A + (size_t)(m0 + row_l + 64) * K + cs;
    const unsigned short* gB0 = BT + (size_t)(n0 + row_l) * K + cs;
    const unsigned short* gB1 = BT + (size_t)(n0 + row_l + 64) * K + cs;

    floatx4 acc[4][4];
#pragma unroll
    for (int i = 0; i < 4; i++)
#pragma unroll
        for (int j = 0; j < 4; j++) acc[i][j] = (floatx4)0.f;

#define GEMM_STAGE(buf, k0)                                                        \
    do {                                                                           \
        __builtin_amdgcn_global_load_lds((gu32*)(gA0 + (k0)),                      \
            (lu32*)(&sA[buf][w * 512]), 16, 0, 0);                                 \
        __builtin_amdgcn_global_load_lds((gu32*)(gA1 + (k0)),                      \
            (lu32*)(&sA[buf][2048 + w * 512]), 16, 0, 0);                          \
        __builtin_amdgcn_global_load_lds((gu32*)(gB0 + (k0)),                      \
            (lu32*)(&sB[buf][w * 512]), 16, 0, 0);                                 \
        __builtin_amdgcn_global_load_lds((gu32*)(gB1 + (k0)),                      \
            (lu32*)(&sB[buf][2048 + w * 512]), 16, 0, 0);                          \
    } while (0)

#define GEMM_COMPUTE(buf)                                                          \
    do {                                                                           \
        short8_t af[4], bfr[4];                                                    \
        _Pragma("unroll")                                                          \
        for (int i = 0; i < 4; i++) {                                              \
            af[i] = *(const short8_t*)(&sA[buf][(wr + i * 16 + lrow) * 32 + quad * 8]); \
            bfr[i] = *(const short8_t*)(&sB[buf][(wc + i * 16 + lrow) * 32 + quad * 8]); \
        }                                                                          \
        _Pragma("unroll")                                                          \
        for (int i = 0; i < 4; i++)                                                \
            _Pragma("unroll")                                                      \
            for (int j = 0; j < 4; j++)                                            \
                acc[i][j] = __builtin_amdgcn_mfma_f32_16x16x32_bf16(               \
                    af[i], bfr[j], acc[i][j], 0, 0, 0);                            \
    } while (0)

    GEMM_STAGE(0, 0);
    __syncthreads();
    int cur = 0;
    for (int k0 = 32; k0 < K; k0 += 32) {
        GEMM_STAGE(cur ^ 1, k0);   // issue next tile
        GEMM_COMPUTE(cur);         // compute current
        __syncthreads();           // drains vmcnt; protects buffer reuse
        cur ^= 1;
    }
    GEMM_COMPUTE(cur);             // last tile

#undef GEMM_STAGE
#undef GEMM_COMPUTE

    if (MODE == 3) {
#pragma unroll
        for (int i = 0; i < 4; i++) {
#pragma unroll
            for (int k = 0; k < 2; k++) {
#pragma unroll
                for (int r = 0; r < 4; r++) {
                    const int gm = m0 + wr + i * 16 + quad * 4 + r;
                    const int pl = n0 + wc + k * 32 + lrow;   // physical l col
                    float lv = acc[i][2 * k][r] + bias[pl];
                    float rv = acc[i][2 * k + 1][r] + bias[pl + 16];
                    const int nlog = (pl >> 5) * 16 + lrow;
                    ((unsigned short*)out)[(size_t)gm * (N >> 1) + nlog] =
                        f2b(gelu_fast(lv) * rv);
                }
            }
        }
    } else {
#pragma unroll
        for (int i = 0; i < 4; i++) {
#pragma unroll
            for (int j = 0; j < 4; j++) {
#pragma unroll
                for (int r = 0; r < 4; r++) {
                    const int gm = m0 + wr + i * 16 + quad * 4 + r;
                    const int gn = n0 + wc + j * 16 + lrow;
                    const size_t idx = (size_t)gm * N + gn;
                    float v = acc[i][j][r] + bias[gn];
                    if (MODE == 0) {
                        ((unsigned short*)out)[idx] = f2b(v);
                    } else {
                        float xcv = b2f(xcb[idx]);
                        float sig = xcv * __builtin_amdgcn_rcpf(1.f + __expf(-xcv));
                        ((unsigned short*)out)[idx] =
                            f2b(sig * (v + b2f(x1b[idx])) + skip[idx]);
                    }
                }
            }
        }
    }
}

// ------------------- sLSTM recurrence + GroupNorm (MFMA) -------------------
// grid (NH=8, B/16=32) = 256 blocks (1/CU), block 1024 (16 waves, 4/SIMD).

#define RECP 516   // f32 row stride for sRec (2-way bank aliasing only)
#define HBP  136   // bf16 row stride for sHb

__global__ __launch_bounds__(1024, 1) void slstm_rec_kernel(
    const float* __restrict__ Rg,             // [8][512][128] f32
    const unsigned short* __restrict__ gxb,   // [B][12][4096] bf16
    const float* __restrict__ gn_g, const float* __restrict__ gn_b,
    unsigned short* __restrict__ hnb)         // [B][12][1024] bf16
{
    __shared__ __align__(16) float sRec[16 * RECP];
    __shared__ __align__(16) unsigned short sHb[16 * HBP];
    const int head = blockIdx.x;
    const int b0 = blockIdx.y * 16;
    const int t = threadIdx.x;
    const int w = t >> 6;
    const int lane = t & 63;
    const int quad = lane >> 4;
    const int l16 = lane & 15;

    short8_t Bf[2][4];
    {
        const float* Rh = Rg + (size_t)head * 65536;
#pragma unroll
        for (int jt = 0; jt < 2; jt++)
#pragma unroll
            for (int kk = 0; kk < 4; kk++) {
                const float* src =
                    Rh + (size_t)(w * 32 + jt * 16 + l16) * 128 + kk * 32 + quad * 8;
                short8_t v;
#pragma unroll
                for (int j = 0; j < 8; j++) v[j] = (short)f2b(src[j]);
                Bf[jt][kk] = v;
            }
    }

    for (int i = t; i < 16 * HBP; i += 1024) sHb[i] = 0;

    const int la = lane;
    float c0 = 0.f, n0s = 0.f, m0 = 0.f;
    float c1 = 0.f, n1s = 0.f, m1 = 0.f;
    const float gg0 = gn_g[head * 128 + la];
    const float gg1 = gn_g[head * 128 + la + 64];
    const float gb0 = gn_b[head * 128 + la];
    const float gb1 = gn_b[head * 128 + la + 64];

    __syncthreads();

    for (int step = 0; step < 12; step++) {
        const unsigned short* gp =
            gxb + ((size_t)(b0 + w) * 12 + step) * 4096 + head * 512;
        float gz0 = b2f(gp[la]),       gz1 = b2f(gp[64 + la]);
        float gi0 = b2f(gp[128 + la]), gi1 = b2f(gp[192 + la]);
        float gf0 = b2f(gp[256 + la]), gf1 = b2f(gp[320 + la]);
        float go0 = b2f(gp[384 + la]), go1 = b2f(gp[448 + la]);

        short8_t Af[4];
#pragma unroll
        for (int kk = 0; kk < 4; kk++)
            Af[kk] = *(const short8_t*)(sHb + l16 * HBP + kk * 32 + quad * 8);
        floatx4 D0 = (floatx4)0.f, D1 = (floatx4)0.f;
#pragma unroll
        for (int kk = 0; kk < 4; kk++) {
            D0 = __builtin_amdgcn_mfma_f32_16x16x32_bf16(Af[kk], Bf[0][kk], D0, 0, 0, 0);
            D1 = __builtin_amdgcn_mfma_f32_16x16x32_bf16(Af[kk], Bf[1][kk], D1, 0, 0, 0);
        }
#pragma unroll
        for (int r = 0; r < 4; r++) {
            sRec[(quad * 4 + r) * RECP + w * 32 + l16] = D0[r];
            sRec[(quad * 4 + r) * RECP + w * 32 + 16 + l16] = D1[r];
        }
        __syncthreads();

        const float* rr = sRec + w * RECP;
        float zp0 = gz0 + rr[la],       zp1 = gz1 + rr[64 + la];
        float ip0 = gi0 + rr[128 + la], ip1 = gi1 + rr[192 + la];
        float fp0 = gf0 + rr[256 + la], fp1 = gf1 + rr[320 + la];
        float op0 = go0 + rr[384 + la], op1 = go1 + rr[448 + la];

        // tanh via sigmoid form + v_rcp (graceful at +/-inf preacts)
        float e20 = __expf(-2.f * zp0), e21 = __expf(-2.f * zp1);
        float z0 = 2.f * __builtin_amdgcn_rcpf(1.f + e20) - 1.f;
        float z1 = 2.f * __builtin_amdgcn_rcpf(1.f + e21) - 1.f;
        float o0 = __builtin_amdgcn_rcpf(1.f + __expf(-op0));
        float o1 = __builtin_amdgcn_rcpf(1.f + __expf(-op1));
        float mn0 = fmaxf(fp0 + m0, ip0), mn1 = fmaxf(fp1 + m1, ip1);
        float ie0 = __expf(ip0 - mn0), ie1 = __expf(ip1 - mn1);
        float fe0 = __expf(fp0 + m0 - mn0), fe1 = __expf(fp1 + m1 - mn1);
        c0 = fe0 * c0 + ie0 * z0;  c1 = fe1 * c1 + ie1 * z1;
        n0s = fe0 * n0s + ie0;     n1s = fe1 * n1s + ie1;
        m0 = mn0;                  m1 = mn1;
        float h0 = o0 * c0 * __builtin_amdgcn_rcpf(n0s);
        float h1 = o1 * c1 * __builtin_amdgcn_rcpf(n1s);

        float s = h0 + h1, ss = h0 * h0 + h1 * h1;
#pragma unroll
        for (int off = 32; off >= 1; off >>= 1) {
            s += __shfl_xor(s, off);
            ss += __shfl_xor(ss, off);
        }
        float mu = s * (1.f / 128.f);
        float var = ss * (1.f / 128.f) - mu * mu;
        float rs = rsqrtf(var + 1e-5f);
        size_t base = ((size_t)(b0 + w) * 12 + step) * 1024 + head * 128;
        hnb[base + la] = f2b((h0 - mu) * rs * gg0 + gb0);
        hnb[base + la + 64] = f2b((h1 - mu) * rs * gg1 + gb1);

        sHb[w * HBP + la] = f2b(h0);
        sHb[w * HBP + la + 64] = f2b(h1);
        __syncthreads();
    }
}

// ---------------- fused tail: conv1+gelu+LN(len)+conv2+skip ----------------
// R16: 2 halves of 24 z-channels (9 barriers, was 17 with 4 quarters).
// grid 512 (one block per batch), block 512 (8 waves), strided pairs
// (p, p+512). lb(512,2) -> 128-VGPR cap so a1[24] (48 VGPR) doesn't spill
// (the old 24-wide attempt spilled under lb(512,6)'s 64-cap).
// LDS: sY 24.6 KB + sZ 49.2 KB = 74 KB; grid-limited 2 blocks/CU unaffected.

__global__ __launch_bounds__(512, 2) void tail_fused_kernel(
    const unsigned short* __restrict__ y, const float* __restrict__ skip,
    const float* __restrict__ w1, const float* __restrict__ b1,
    const float* __restrict__ w2, const float* __restrict__ b2,
    const float* __restrict__ lng, const float* __restrict__ lnb,
    float* __restrict__ out)
{
    __shared__ unsigned short sY[12][1026];   // 24.6 KB
    __shared__ unsigned short sZ[24][1026];   // 49.2 KB
    __shared__ float sMR[24][2];
    const int b = blockIdx.x;
    const int t = threadIdx.x;
    const int p = t;                          // positions p, p+512
    const size_t boff = (size_t)b * 12288;

    {
        const u32* gy = (const u32*)(y + boff);
#pragma unroll
        for (int ci = 0; ci < 12; ci++)
            ((u32*)&sY[ci][0])[t] = gy[ci * 512 + t];
    }
    // LN gains for the dword-mapped normalize pass (positions 2t, 2t+1)
    const float lgA = lng[2 * t], lbA = lnb[2 * t];
    const float lgB = lng[2 * t + 1], lbB = lnb[2 * t + 1];
    __syncthreads();

    float2_t acc[12];
#pragma unroll
    for (int o = 0; o < 12; o++) { float bv = b2[o]; acc[o] = float2_t{bv, bv}; }

    for (int h = 0; h < 2; h++) {
        // ---- conv1: 12 in -> this half's 24 out channels, ci-outer
        float2_t a1[24];
#pragma unroll
        for (int o = 0; o < 24; o++) {
            float bo = b1[h * 24 + o];
            a1[o] = float2_t{bo, bo};
        }
        for (int ci = 0; ci < 12; ci++) {
            float2_t v0 = float2_t{b2f(sY[ci][p]), b2f(sY[ci][p + 512])};
            float2_t vm = float2_t{(p > 0) ? b2f(sY[ci][p - 1]) : 0.f,
                                   b2f(sY[ci][p + 511])};
            float2_t vp = float2_t{b2f(sY[ci][p + 1]),
                                   (p < 511) ? b2f(sY[ci][p + 513]) : 0.f};
            const float* wp = w1 + ci * 3;             // uniform -> SGPR
#pragma unroll
            for (int o = 0; o < 24; o++) {
                const float* wo = wp + (h * 24 + o) * 36;
                a1[o] += vm * wo[0] + v0 * wo[1] + vp * wo[2];
            }
        }
#pragma unroll
        for (int o = 0; o < 24; o++) {
            sZ[o][p] = f2b(gelu_fast(a1[o].x));
            sZ[o][p + 512] = f2b(gelu_fast(a1[o].y));
        }
        __syncthreads();

        // ---- LN stats: wave wv handles ch wv, wv+8, wv+16
        {
            const int wv = t >> 6, la = t & 63;
#pragma unroll
            for (int j = 0; j < 3; j++) {
                const int ch = wv + j * 8;
                float s = 0.f, ss = 0.f;
#pragma unroll
                for (int u = 0; u < 8; u++) {
                    float2_t v = make2u(((const u32*)&sZ[ch][0])[la + u * 64]);
                    s += v.x + v.y;
                    ss += v.x * v.x + v.y * v.y;
                }
#pragma unroll
                for (int off = 32; off >= 1; off >>= 1) {
                    s += __shfl_xor(s, off);
                    ss += __shfl_xor(ss, off);
                }
                if (la == 0) {
                    float mu = s * (1.f / 1024.f);
                    float var = ss * (1.f / 1024.f) - mu * mu;
                    sMR[ch][0] = mu;
                    sMR[ch][1] = rsqrtf(var + 1e-5f);
                }
            }
        }
        __syncthreads();

        // ---- normalize in place (dword mapping: one b32 read+write per ch)
#pragma unroll
        for (int ch = 0; ch < 24; ch++) {
            const float mu = sMR[ch][0], rs = sMR[ch][1];
            float2_t f = make2u(((const u32*)&sZ[ch][0])[t]);
            f.x = (f.x - mu) * rs * lgA + lbA;
            f.y = (f.y - mu) * rs * lgB + lbB;
            ((u32*)&sZ[ch][0])[t] = pack2(f.x, f.y);
        }
        __syncthreads();

        // ---- conv2 partial over this half's 24 input channels
        for (int ci = 0; ci < 24; ci++) {
            float2_t z0 = float2_t{b2f(sZ[ci][p]), b2f(sZ[ci][p + 512])};
            float2_t zm = float2_t{(p > 0) ? b2f(sZ[ci][p - 1]) : 0.f,
                                   b2f(sZ[ci][p + 511])};
            float2_t zp = float2_t{b2f(sZ[ci][p + 1]),
                                   (p < 511) ? b2f(sZ[ci][p + 513]) : 0.f};
            const float* wp = w2 + (h * 24 + ci) * 3;  // uniform -> SGPR
#pragma unroll
            for (int o = 0; o < 12; o++)
                acc[o] += zm * wp[o * 144] + z0 * wp[o * 144 + 1]
                        + zp * wp[o * 144 + 2];
        }
        __syncthreads();   // before next half overwrites sZ
    }

#pragma unroll
    for (int o = 0; o < 12; o++) {
        size_t i0 = boff + (size_t)o * 1024 + p;
        out[i0] = acc[o].x + skip[i0];
        out[i0 + 512] = acc[o].y + skip[i0 + 512];
    }
}

// ------------------------------ launcher -----------------------------------

extern "C" void kernel_launch(void* const* d_in, const int* in_sizes, int n_in,
                              void* d_out, int out_size, void* d_ws, size_t ws_size,
                              hipStream_t stream)
{
    (void)in_sizes; (void)n_in; (void)out_size; (void)ws_size;
    const float* x      = (const float*)d_in[0];
    const float* ln_g   = (const float*)d_in[1];
    const float* ln_b   = (const float*)d_in[2];
    const float* fc1_w  = (const float*)d_in[3];
    const float* fc1_b  = (const float*)d_in[4];
    const float* fc2_w  = (const float*)d_in[5];
    const float* fc2_b  = (const float*)d_in[6];
    const float* conv1_w= (const float*)d_in[7];
    const float* conv1_b= (const float*)d_in[8];
    const float* conv2_w= (const float*)d_in[9];
    const float* conv2_b= (const float*)d_in[10];
    const float* xl_g   = (const float*)d_in[11];
    const float* xl_b   = (const float*)d_in[12];
    const float* Wg     = (const float*)d_in[13];
    const float* bg     = (const float*)d_in[14];
    const float* Rg     = (const float*)d_in[15];
    const float* gn_g   = (const float*)d_in[16];
    const float* gn_b   = (const float*)d_in[17];
    const float* upl_w  = (const float*)d_in[18];
    const float* upl_b  = (const float*)d_in[19];
    const float* upr_w  = (const float*)d_in[20];
    const float* upr_b  = (const float*)d_in[21];
    const float* down_w = (const float*)d_in[22];
    const float* down_b = (const float*)d_in[23];

    char* ws = (char*)d_ws;
    size_t off = 0;
    auto alloc = [&](size_t bytes) -> char* {
        char* p = ws + off;
        off = (off + bytes + 255) & ~(size_t)255;
        return p;
    };
    float* xn            = (float*)alloc(25165824);          // 6144x1024 f32
    unsigned short* xcb  = (unsigned short*)alloc(12582912); // 6144x1024 bf16
    unsigned short* x1b  = (unsigned short*)alloc(12582912);
    unsigned short* xn2b = (unsigned short*)alloc(12582912);
    unsigned short* gxb  = (unsigned short*)alloc(50331648); // 6144x4096 bf16
    unsigned short* hnb  = (unsigned short*)alloc(12582912);
    unsigned short* glrb = (unsigned short*)alloc(12582912); // 6144x1024 bf16
    unsigned short* yb   = (unsigned short*)alloc(12582912); // 6144x1024 bf16
    unsigned short* WgT  = (unsigned short*)alloc(8388608);  // 4096x1024 bf16
    unsigned short* WupT = (unsigned short*)alloc(4194304);  // 2048x1024 bf16 (interleaved)
    unsigned short* WdT  = (unsigned short*)alloc(2097152);  // 1024x1024 bf16
    float* bup           = (float*)alloc(8192);              // 2048 f32 (interleaved)

    // weight prep
    transpose_bf16_k<<<dim3(128, 32), 256, 0, stream>>>(Wg, WgT, 1024, 4096, 16, 0);
    transpose_bf16_k<<<dim3(32, 32), 256, 0, stream>>>(upl_w, WupT, 1024, 1024, 32, 0);
    transpose_bf16_k<<<dim3(32, 32), 256, 0, stream>>>(upr_w, WupT, 1024, 1024, 32, 16);
    transpose_bf16_k<<<dim3(32, 32), 256, 0, stream>>>(down_w, WdT, 1024, 1024, 16, 0);
    bias_ilv_kernel<<<8, 256, 0, stream>>>(upl_b, upr_b, bup);

    // main pipeline
    ln_fc_kernel<<<512, 512, 0, stream>>>(
        x, ln_g, ln_b, xl_g, xl_b, fc1_w, fc1_b, fc2_w, fc2_b,
        xn, xcb, x1b, xn2b);
    gemm_kernel<0><<<dim3(32, 48), 256, 0, stream>>>(
        xn2b, WgT, bg, gxb, 6144, 4096, 1024, nullptr, nullptr, nullptr);
    slstm_rec_kernel<<<dim3(8, 32), 1024, 0, stream>>>(Rg, gxb, gn_g, gn_b, hnb);
    gemm_kernel<3><<<dim3(16, 48), 256, 0, stream>>>(
        hnb, WupT, bup, glrb, 6144, 2048, 1024, nullptr, nullptr, nullptr);
    gemm_kernel<2><<<dim3(8, 48), 256, 0, stream>>>(
        glrb, WdT, down_b, yb, 6144, 1024, 1024, xcb, x1b, xn);
    tail_fused_kernel<<<512, 512, 0, stream>>>(
        yb, xn, conv1_w, conv1_b, conv2_w, conv2_b, ln_g, ln_b, (float*)d_out);
}